// Round 10
// baseline (490.714 us; speedup 1.0000x reference)
//
#include <hip/hip_runtime.h>
#include <hip/hip_bf16.h>
#include <math.h>

// Problem dims
#define T_ 2048
#define B_ 2
#define D_ 1024
#define H_ 16
#define F_ 4096
#define E_ 8
#define N_ 4096      // T_*B_ tokens, row r = t*B_ + b (memory order of x[T,B,D])
#define HD_ 64
#define PADROWS 5120 // N_ + E_*128 worst-case padded rows

typedef __attribute__((ext_vector_type(8))) short short8_t;
typedef __attribute__((ext_vector_type(4))) float f32x4_t;
typedef __attribute__((ext_vector_type(16))) float f32x16_t;
typedef __attribute__((ext_vector_type(4))) unsigned u32x4_t;

__device__ __forceinline__ unsigned short f2bf(float f) {
    union { float f; unsigned u; } a; a.f = f;
    unsigned r = a.u + 0x7FFFu + ((a.u >> 16) & 1u);   // RNE
    return (unsigned short)(r >> 16);
}

__device__ __forceinline__ unsigned cvtpk(float lo, float hi) {
    unsigned r;
    asm("v_cvt_pk_bf16_f32 %0, %1, %2" : "=v"(r) : "v"(lo), "v"(hi));
    return r;
}

__device__ __forceinline__ void glds16(const unsigned short* g, unsigned short* l) {
    __builtin_amdgcn_global_load_lds(
        (const __attribute__((address_space(1))) void*)g,
        (__attribute__((address_space(3))) void*)l, 16, 0, 0);
}

__device__ __forceinline__ void blockReduce2(float& a, float& b, float* sm) {
    #pragma unroll
    for (int m = 32; m; m >>= 1) { a += __shfl_xor(a, m); b += __shfl_xor(b, m); }
    const int w = threadIdx.x >> 6, l = threadIdx.x & 63;
    __syncthreads();
    if (l == 0) { sm[w] = a; sm[8 + w] = b; }
    __syncthreads();
    a = sm[0] + sm[1] + sm[2] + sm[3];
    b = sm[8] + sm[9] + sm[10] + sm[11];
}

// ---------- transpose + fp32->bf16 convert: out[c*R+r] = in[r*C+c] ----------
__global__ __launch_bounds__(256) void k_transpose(const float* __restrict__ in,
                                                   unsigned short* __restrict__ out,
                                                   int R, int C) {
    __shared__ float tile[32][33];
    const int c0 = blockIdx.x * 32, r0 = blockIdx.y * 32;
    const size_t base = (size_t)blockIdx.z * R * C;
    in += base; out += base;
    const int tx = threadIdx.x & 31, ty = threadIdx.x >> 5; // ty 0..7
    #pragma unroll
    for (int i = 0; i < 32; i += 8)
        tile[ty + i][tx] = in[(size_t)(r0 + ty + i) * C + c0 + tx];
    __syncthreads();
    #pragma unroll
    for (int i = 0; i < 32; i += 8)
        out[(size_t)(c0 + ty + i) * R + r0 + tx] = f2bf(tile[tx][ty + i]);
}

// ---------- bf16 transpose for V: [32][T][HD] -> [32][HD][T] ----------
__global__ __launch_bounds__(256) void k_transpose_v(const unsigned short* __restrict__ in,
                                                     unsigned short* __restrict__ out) {
    const int bh = blockIdx.x;
    const int t0 = blockIdx.y * 128;
    const int tid = threadIdx.x;
    const int hd = tid & 63;
    const size_t ib = (size_t)bh * T_ * HD_;
    const size_t ob = (size_t)bh * HD_ * T_;
    for (int tb = tid >> 6; tb < 16; tb += 4) {
        const int t = t0 + tb * 8;
        short8_t v;
        #pragma unroll
        for (int k = 0; k < 8; ++k)
            v[k] = (short)in[ib + (size_t)(t + k) * HD_ + hd];   // coalesced 128B/lane-group
        *(short8_t*)(out + ob + (size_t)hd * T_ + t) = v;
    }
}

// ---------- LayerNorm (fp32 in, bf16 out), one block per row ----------
__global__ __launch_bounds__(256) void k_ln(const float* __restrict__ x,
                                            const float* __restrict__ g,
                                            const float* __restrict__ b,
                                            unsigned short* __restrict__ out) {
    __shared__ float sm[16];
    const int row = blockIdx.x, tid = threadIdx.x;
    const float4 v = *(const float4*)(x + (size_t)row * D_ + tid * 4);
    float s1 = v.x + v.y + v.z + v.w;
    float s2 = v.x * v.x + v.y * v.y + v.z * v.z + v.w * v.w;
    blockReduce2(s1, s2, sm);
    const float mean = s1 * (1.f / D_);
    const float inv  = rsqrtf(s2 * (1.f / D_) - mean * mean + 1e-5f);
    const float4 gg = *(const float4*)(g + tid * 4);
    const float4 bb = *(const float4*)(b + tid * 4);
    unsigned long long pk =
          (unsigned long long)f2bf((v.x - mean) * inv * gg.x + bb.x)
        | ((unsigned long long)f2bf((v.y - mean) * inv * gg.y + bb.y) << 16)
        | ((unsigned long long)f2bf((v.z - mean) * inv * gg.z + bb.z) << 32)
        | ((unsigned long long)f2bf((v.w - mean) * inv * gg.w + bb.w) << 48);
    *(unsigned long long*)(out + (size_t)row * D_ + tid * 4) = pk;
}

// ---------- init kernels for split-K accumulation ----------
__global__ __launch_bounds__(256) void k_init_x2(const float* __restrict__ x,
                                                 const float* __restrict__ bo,
                                                 float* __restrict__ x2) {
    const int row = blockIdx.x, tid = threadIdx.x;
    const size_t idx = (size_t)row * D_ + tid * 4;
    const float4 v = *(const float4*)(x + idx);
    const float4 b = *(const float4*)(bo + tid * 4);
    float4 o; o.x = v.x + b.x; o.y = v.y + b.y; o.z = v.z + b.z; o.w = v.w + b.w;
    *(float4*)(x2 + idx) = o;
}

__global__ __launch_bounds__(256) void k_init_out(const float* __restrict__ x2u,
                                                  const float* __restrict__ eb2,
                                                  const int* __restrict__ assign,
                                                  float* __restrict__ out) {
    const int row = blockIdx.x, tid = threadIdx.x;
    const int e = assign[row];
    const size_t idx = (size_t)row * D_ + tid * 4;
    const float4 v = *(const float4*)(x2u + idx);
    const float4 b = *(const float4*)(eb2 + (size_t)e * D_ + tid * 4);
    float4 o; o.x = v.x + b.x; o.y = v.y + b.y; o.z = v.z + b.z; o.w = v.w + b.w;
    *(float4*)(out + idx) = o;
}

// ---------- shared 128x128xK bf16 GEMM core, 3-buffer depth-2 pipeline (T3+T4+T2) ----------
// Counted vmcnt: tiles k+1,k+2 stay in flight across barriers; vmcnt(4) releases tile k.
// T2 LDS swizzle (rule 21): LDS dest stays linear [row][32k]; the global SOURCE column is
// pre-permuted (slot ^= (row>>1)&3, done in the callers' `cs`), and reads XOR the same
// pattern (fgs below). Breaks the 8-way bank conflict of the 64B-row layout to 2-way (free).
__device__ __forceinline__ void gemm_core(const unsigned short* ap0, const unsigned short* ap1,
                                          const unsigned short* bp0, const unsigned short* bp1,
                                          int K, unsigned short* Als, unsigned short* Bls,
                                          f32x4_t (&acc)[4][4]) {
    const int tid = threadIdx.x, w = tid >> 6, l = tid & 63;
    const int wm = (w >> 1) * 64, wn = (w & 1) * 64;
    const int fr = l & 15, fg = (l >> 4) * 8;
    const int fgs = fg ^ (((fr >> 1) & 3) << 3);   // swizzled k-slot for this lane's rows
    f32x4_t z4 = {0.f, 0.f, 0.f, 0.f};
    #pragma unroll
    for (int m = 0; m < 4; m++)
        #pragma unroll
        for (int n = 0; n < 4; n++) acc[m][n] = z4;
    // prologue: stage tiles 0 and 1 into buffers 0 and 1
    glds16(ap0, Als + w * 512);
    glds16(ap1, Als + (w + 4) * 512);
    glds16(bp0, Bls + w * 512);
    glds16(bp1, Bls + (w + 4) * 512);
    ap0 += 32; ap1 += 32; bp0 += 32; bp1 += 32;
    glds16(ap0, Als + 4096 + w * 512);
    glds16(ap1, Als + 4096 + (w + 4) * 512);
    glds16(bp0, Bls + 4096 + w * 512);
    glds16(bp1, Bls + 4096 + (w + 4) * 512);
    ap0 += 32; ap1 += 32; bp0 += 32; bp1 += 32;
    unsigned c0 = 0, c1 = 4096, c2 = 8192;   // compute / in-flight / issue targets
    const int nk = K >> 5;
    for (int kt = 0; kt < nk; ++kt) {
        if (kt < nk - 1) asm volatile("s_waitcnt vmcnt(4)" ::: "memory");
        else             asm volatile("s_waitcnt vmcnt(0)" ::: "memory");
        __builtin_amdgcn_s_barrier();
        __builtin_amdgcn_sched_barrier(0);
        short8_t a[4], b[4];
        #pragma unroll
        for (int m = 0; m < 4; m++) a[m] = *(const short8_t*)(Als + c0 + (wm + m * 16 + fr) * 32 + fgs);
        #pragma unroll
        for (int n = 0; n < 4; n++) b[n] = *(const short8_t*)(Bls + c0 + (wn + n * 16 + fr) * 32 + fgs);
        #pragma unroll
        for (int m = 0; m < 4; m++)
            #pragma unroll
            for (int n = 0; n < 4; n++)
                acc[m][n] = __builtin_amdgcn_mfma_f32_16x16x32_bf16(a[m], b[n], acc[m][n], 0, 0, 0);
        if (kt + 2 < nk) {                    // issue tile k+2 into the retired buffer
            glds16(ap0, Als + c2 + w * 512);
            glds16(ap1, Als + c2 + (w + 4) * 512);
            glds16(bp0, Bls + c2 + w * 512);
            glds16(bp1, Bls + c2 + (w + 4) * 512);
            ap0 += 32; ap1 += 32; bp0 += 32; bp1 += 32;
        }
        const unsigned t = c0; c0 = c1; c1 = c2; c2 = t;
    }
}

// ---------- GEMM: h1 @ [Wq|Wk|Wv] + bias, scale q, scatter into [B,H,T,HD] ----------
__global__ __launch_bounds__(256) void k_gemm_qkv(
    const unsigned short* __restrict__ A, const unsigned short* __restrict__ BT,
    const float* __restrict__ bq, const float* __restrict__ bk, const float* __restrict__ bv,
    unsigned short* __restrict__ Qb, unsigned short* __restrict__ Kb, unsigned short* __restrict__ Vb) {
    __shared__ unsigned short Als[12288], Bls[12288];
    const int tid = threadIdx.x, w = tid >> 6, l = tid & 63;
    const int col0 = blockIdx.x * 128, row0 = blockIdx.y * 128;
    const int r0s = w * 16 + (l >> 2), r1s = 64 + w * 16 + (l >> 2);
    const int cs = ((l & 3) ^ ((l >> 3) & 3)) * 8;   // T2 pre-swizzled source slot
    const unsigned short* ap0 = A + (size_t)(row0 + r0s) * D_ + cs;
    const unsigned short* ap1 = A + (size_t)(row0 + r1s) * D_ + cs;
    const unsigned short* bp0 = BT + (size_t)(col0 + r0s) * D_ + cs;
    const unsigned short* bp1 = BT + (size_t)(col0 + r1s) * D_ + cs;
    f32x4_t acc[4][4];
    gemm_core(ap0, ap1, bp0, bp1, D_, Als, Bls, acc);
    const int wm = (w >> 1) * 64, wn = (w & 1) * 64, fr = l & 15, fg4 = l >> 4;
    #pragma unroll
    for (int n = 0; n < 4; n++) {
        const int gcol = col0 + wn + n * 16 + fr;
        const int which = gcol >> 10, dc = gcol & 1023;
        const float bias = which == 0 ? bq[dc] : (which == 1 ? bk[dc] : bv[dc]);
        unsigned short* dst = which == 0 ? Qb : (which == 1 ? Kb : Vb);
        const int hh = dc >> 6, hd = dc & 63;
        #pragma unroll
        for (int m = 0; m < 4; m++)
            #pragma unroll
            for (int rr = 0; rr < 4; rr++) {
                const int grow = row0 + wm + m * 16 + fg4 * 4 + rr;
                float v = acc[m][n][rr] + bias;
                if (which == 0) v *= 0.1803368801111204f; // HD^-0.5 * log2(e)
                const int t = grow >> 1, bb = grow & 1;
                dst[((size_t)(bb * H_ + hh) * T_ + t) * HD_ + hd] = f2bf(v);
            }
    }
}

// ---------- causal flash attention v5: swapped QK^T, 32x32 MFMA, in-register softmax ----------
__global__ __launch_bounds__(256) void k_attn(const unsigned short* __restrict__ Qb,
                                              const unsigned short* __restrict__ Kb,
                                              const unsigned short* __restrict__ Vt,
                                              unsigned short* __restrict__ aout) {
    __shared__ unsigned short Kl[2][4096];   // [buf][64 kv][64 hd] linear, swizzled content
    __shared__ unsigned short Vl[2][4096];   // [buf][64 hd][64 kv] linear, swizzled content
    const int id = blockIdx.x;
    const int qt = (id < 256) ? (15 - (id & 15)) : (id & 15);
    const int bh = (id >> 4) & 31;
    const int tid = threadIdx.x, w = tid >> 6, l = tid & 63;
    const int q5 = l & 31, hi = l >> 5, l7 = l & 7;
    const int row0 = w * 8 + (l >> 3);             // staging row (0..31)
    const int swz = ((l & 7) ^ (l >> 3)) * 8;      // pre-swizzled source column (elements)
    const size_t base = (size_t)bh * T_ * HD_;
    const unsigned short* Qp = Qb + base;
    const unsigned short* kps = Kb + base + (size_t)row0 * HD_ + swz;
    const unsigned short* vps = Vt + base + (size_t)row0 * T_ + swz;  // [HD][T]
    const int qw0 = qt * 128 + w * 32;
    const int q = qw0 + q5;

    short8_t aq[4];
    #pragma unroll
    for (int khd = 0; khd < 4; ++khd)
        aq[khd] = *(const short8_t*)(Qp + (size_t)q * HD_ + khd * 16 + hi * 8);

    f32x16_t accO0, accO1;
    #pragma unroll
    for (int i = 0; i < 16; ++i) { accO0[i] = 0.f; accO1[i] = 0.f; }
    float mrun = -1e30f, lrun = 0.f;

    const int niter = (qt + 1) * 2;

    glds16(kps,            &Kl[0][w * 512]);
    glds16(kps + 32 * HD_, &Kl[0][2048 + w * 512]);
    glds16(vps,            &Vl[0][w * 512]);
    glds16(vps + 32 * T_,  &Vl[0][2048 + w * 512]);
    asm volatile("s_waitcnt vmcnt(0)" ::: "memory");
    __syncthreads();

    for (int it = 0; it < niter; ++it) {
        const int cur = it & 1;
        const int s0 = it * 64;
        if (it + 1 < niter) {
            const size_t ko = (size_t)(it + 1) * 64 * HD_;
            const int vo = (it + 1) * 64;
            glds16(kps + ko,            &Kl[cur ^ 1][w * 512]);
            glds16(kps + ko + 32 * HD_, &Kl[cur ^ 1][2048 + w * 512]);
            glds16(vps + vo,            &Vl[cur ^ 1][w * 512]);
            glds16(vps + vo + 32 * T_,  &Vl[cur ^ 1][2048 + w * 512]);
        }
        if (s0 <= qw0 + 31) {
            const unsigned short* KT = Kl[cur];
            const unsigned short* VT = Vl[cur];

            f32x16_t st0, st1;
            #pragma unroll
            for (int i = 0; i < 16; ++i) { st0[i] = 0.f; st1[i] = 0.f; }
            #pragma unroll
            for (int khd = 0; khd < 4; ++khd) {
                const int cb = (khd * 16 + hi * 8) ^ (l7 * 8);
                const short8_t k0 = *(const short8_t*)(KT + q5 * 64 + cb);
                const short8_t k1 = *(const short8_t*)(KT + (32 + q5) * 64 + cb);
                st0 = __builtin_amdgcn_mfma_f32_32x32x16_bf16(k0, aq[khd], st0, 0, 0, 0);
                st1 = __builtin_amdgcn_mfma_f32_32x32x16_bf16(k1, aq[khd], st1, 0, 0, 0);
            }

            const bool domask = (s0 + 63 > qw0);
            float pmax = -3e38f;
            #pragma unroll
            for (int r = 0; r < 16; ++r) {
                float v0 = st0[r], v1 = st1[r];
                if (domask) {
                    const int kv0 = s0 + (r & 3) + 8 * (r >> 2) + 4 * hi;
                    if (kv0 > q)      v0 = -1e30f;
                    if (kv0 + 32 > q) v1 = -1e30f;
                }
                st0[r] = v0; st1[r] = v1;
                pmax = fmaxf(pmax, fmaxf(v0, v1));
            }
            pmax = fmaxf(pmax, __shfl_xor(pmax, 32));
            const float mnew = fmaxf(mrun, pmax);
            const float scl = exp2f(mrun - mnew);
            float pt0[16], pt1[16];
            float rs = 0.f;
            #pragma unroll
            for (int r = 0; r < 16; ++r) {
                pt0[r] = exp2f(st0[r] - mnew);
                pt1[r] = exp2f(st1[r] - mnew);
                rs += pt0[r] + pt1[r];
            }
            rs += __shfl_xor(rs, 32);
            lrun = lrun * scl + rs;
            mrun = mnew;
            #pragma unroll
            for (int i = 0; i < 16; ++i) { accO0[i] *= scl; accO1[i] *= scl; }

            unsigned Wp[2][4][2];
            #pragma unroll
            for (int b = 0; b < 4; ++b) {
                Wp[0][b][0] = cvtpk(pt0[4 * b + 0], pt0[4 * b + 1]);
                Wp[0][b][1] = cvtpk(pt0[4 * b + 2], pt0[4 * b + 3]);
                Wp[1][b][0] = cvtpk(pt1[4 * b + 0], pt1[4 * b + 1]);
                Wp[1][b][1] = cvtpk(pt1[4 * b + 2], pt1[4 * b + 3]);
            }

            #pragma unroll
            for (int ks = 0; ks < 4; ++ks) {
                const int t = ks >> 1, b0 = (ks & 1) * 2;
                const unsigned ownA0 = Wp[t][b0][0],     ownA1 = Wp[t][b0][1];
                const unsigned ownB0 = Wp[t][b0 + 1][0], ownB1 = Wp[t][b0 + 1][1];
                const unsigned send0 = hi ? ownA0 : ownB0;
                const unsigned send1 = hi ? ownA1 : ownB1;
                const unsigned recv0 = __shfl_xor(send0, 32);
                const unsigned recv1 = __shfl_xor(send1, 32);
                u32x4_t wds;
                wds[0] = hi ? recv0 : ownA0;
                wds[1] = hi ? recv1 : ownA1;
                wds[2] = hi ? ownB0 : recv0;
                wds[3] = hi ? ownB1 : recv1;
                const short8_t pfrag = __builtin_bit_cast(short8_t, wds);
                const int cb = (ks * 16 + hi * 8) ^ (l7 * 8);
                const short8_t v0 = *(const short8_t*)(VT + q5 * 64 + cb);
                const short8_t v1 = *(const short8_t*)(VT + (32 + q5) * 64 + cb);
                accO0 = __builtin_amdgcn_mfma_f32_32x32x16_bf16(v0, pfrag, accO0, 0, 0, 0);
                accO1 = __builtin_amdgcn_mfma_f32_32x32x16_bf16(v1, pfrag, accO1, 0, 0, 0);
            }
        }
        asm volatile("s_waitcnt vmcnt(0)" ::: "memory");
        __syncthreads();
    }

    const float linv = 1.f / lrun;
    const int bidx = bh >> 4, hidx = bh & 15;
    unsigned short* orow = aout + (size_t)(q * B_ + bidx) * D_ + hidx * 64;
    #pragma unroll
    for (int g = 0; g < 4; ++g) {
        const int hd0 = 8 * g + 4 * hi;
        unsigned long long pk0 =
              (unsigned long long)f2bf(accO0[4 * g + 0] * linv)
            | ((unsigned long long)f2bf(accO0[4 * g + 1] * linv) << 16)
            | ((unsigned long long)f2bf(accO0[4 * g + 2] * linv) << 32)
            | ((unsigned long long)f2bf(accO0[4 * g + 3] * linv) << 48);
        *(unsigned long long*)(orow + hd0) = pk0;
        unsigned long long pk1 =
              (unsigned long long)f2bf(accO1[4 * g + 0] * linv)
            | ((unsigned long long)f2bf(accO1[4 * g + 1] * linv) << 16)
            | ((unsigned long long)f2bf(accO1[4 * g + 2] * linv) << 32)
            | ((unsigned long long)f2bf(accO1[4 * g + 3] * linv) << 48);
        *(unsigned long long*)(orow + 32 + hd0) = pk1;
    }
}

// ---------- O-projection, split-K=2: x2 += aout @ Wo (atomic; x2 pre-init with x+bo) ----------
// grid (rows=32, cols=8, kc=2)
__global__ __launch_bounds__(256) void k_gemm_o(
    const unsigned short* __restrict__ A, const unsigned short* __restrict__ BT,
    float* __restrict__ x2) {
    __shared__ unsigned short Als[12288], Bls[12288];
    const int tid = threadIdx.x, w = tid >> 6, l = tid & 63;
    const int row0 = blockIdx.x * 128, col0 = blockIdx.y * 128;
    const int kc = blockIdx.z * 512;
    const int r0s = w * 16 + (l >> 2), r1s = 64 + w * 16 + (l >> 2);
    const int cs = ((l & 3) ^ ((l >> 3) & 3)) * 8;   // T2 pre-swizzled source slot
    const unsigned short* ap0 = A + (size_t)(row0 + r0s) * D_ + kc + cs;
    const unsigned short* ap1 = A + (size_t)(row0 + r1s) * D_ + kc + cs;
    const unsigned short* bp0 = BT + (size_t)(col0 + r0s) * D_ + kc + cs;
    const unsigned short* bp1 = BT + (size_t)(col0 + r1s) * D_ + kc + cs;
    f32x4_t acc[4][4];
    gemm_core(ap0, ap1, bp0, bp1, 512, Als, Bls, acc);
    const int wm = (w >> 1) * 64, wn = (w & 1) * 64, fr = l & 15, fg4 = l >> 4;
    #pragma unroll
    for (int n = 0; n < 4; n++) {
        const int gcol = col0 + wn + n * 16 + fr;
        #pragma unroll
        for (int m = 0; m < 4; m++)
            #pragma unroll
            for (int rr = 0; rr < 4; rr++) {
                const int grow = row0 + wm + m * 16 + fg4 * 4 + rr;
                atomicAdd(&x2[(size_t)grow * D_ + gcol], acc[m][n][rr]);
            }
    }
}

// ---------- LN2 + gating + expert-LN; x2 <- x2 + u (in place) ----------
__global__ __launch_bounds__(256) void k_ln2_gate(
    float* __restrict__ x2, const float* __restrict__ g2, const float* __restrict__ b2,
    const float* __restrict__ cent, const float* __restrict__ eg, const float* __restrict__ eb,
    unsigned short* __restrict__ z, int* __restrict__ assign, int* __restrict__ counts) {
    __shared__ float sm[48];
    const int row = blockIdx.x, tid = threadIdx.x;
    const int w = tid >> 6, l = tid & 63;
    float* xr = x2 + (size_t)row * D_;
    const float4 v = *(const float4*)(xr + tid * 4);
    float s1 = v.x + v.y + v.z + v.w;
    float s2 = v.x * v.x + v.y * v.y + v.z * v.z + v.w * v.w;
    blockReduce2(s1, s2, sm);
    const float mean = s1 * (1.f / D_);
    const float inv  = rsqrtf(s2 * (1.f / D_) - mean * mean + 1e-5f);
    const float4 gg = *(const float4*)(g2 + tid * 4), bb = *(const float4*)(b2 + tid * 4);
    float4 u;
    u.x = (v.x - mean) * inv * gg.x + bb.x;
    u.y = (v.y - mean) * inv * gg.y + bb.y;
    u.z = (v.z - mean) * inv * gg.z + bb.z;
    u.w = (v.w - mean) * inv * gg.w + bb.w;
    float p[E_];
    #pragma unroll
    for (int e = 0; e < E_; e++) {
        const float4 c = *(const float4*)(cent + (size_t)e * D_ + tid * 4);
        p[e] = u.x * c.x + u.y * c.y + u.z * c.z + u.w * c.w;
    }
    #pragma unroll
    for (int m = 32; m; m >>= 1)
        #pragma unroll
        for (int e = 0; e < E_; e++) p[e] += __shfl_xor(p[e], m);
    __syncthreads();
    if (l == 0) {
        #pragma unroll
        for (int e = 0; e < E_; e++) sm[16 + e * 4 + w] = p[e];
    }
    __syncthreads();
    int best = 0; float bl = -1e30f;
    #pragma unroll
    for (int e = 0; e < E_; e++) {
        const float le = sm[16 + e * 4] + sm[16 + e * 4 + 1] + sm[16 + e * 4 + 2] + sm[16 + e * 4 + 3];
        if (le > bl) { bl = le; best = e; }
    }
    float t1 = u.x + u.y + u.z + u.w;
    float t2 = u.x * u.x + u.y * u.y + u.z * u.z + u.w * u.w;
    blockReduce2(t1, t2, sm);
    const float m2   = t1 * (1.f / D_);
    const float inv2 = rsqrtf(t2 * (1.f / D_) - m2 * m2 + 1e-5f);
    const float4 egv = *(const float4*)(eg + (size_t)best * D_ + tid * 4);
    const float4 ebv = *(const float4*)(eb + (size_t)best * D_ + tid * 4);
    unsigned long long pk =
          (unsigned long long)f2bf((u.x - m2) * inv2 * egv.x + ebv.x)
        | ((unsigned long long)f2bf((u.y - m2) * inv2 * egv.y + ebv.y) << 16)
        | ((unsigned long long)f2bf((u.z - m2) * inv2 * egv.z + ebv.z) << 32)
        | ((unsigned long long)f2bf((u.w - m2) * inv2 * egv.w + ebv.w) << 48);
    *(unsigned long long*)(z + (size_t)row * D_ + tid * 4) = pk;
    float4 xu; xu.x = v.x + u.x; xu.y = v.y + u.y; xu.z = v.z + u.z; xu.w = v.w + u.w;
    *(float4*)(xr + tid * 4) = xu;
    if (tid == 0) { assign[row] = best; atomicAdd(&counts[best], 1); }
}

// ---------- routing bookkeeping ----------
__global__ void k_init(int* counts, int* cursor, int* perm) {
    const int t = threadIdx.x;
    if (t < E_) { counts[t] = 0; cursor[t] = 0; }
    for (int i = t; i < PADROWS; i += 256) perm[i] = -1;
}

__global__ void k_offsets(const int* counts, int* pad_off) {
    if (threadIdx.x == 0) {
        int o = 0; pad_off[0] = 0;
        for (int e = 0; e < E_; e++) { o += ((counts[e] + 127) >> 7) << 7; pad_off[e + 1] = o; }
    }
}

__global__ void k_scatter(const int* assign, const int* pad_off, int* cursor, int* perm) {
    const int r = blockIdx.x * 256 + threadIdx.x;
    if (r >= N_) return;
    const int e = assign[r];
    const int pos = pad_off[e] + atomicAdd(&cursor[e], 1);
    perm[pos] = r;
}

// ---------- expert FFN GEMM 1: Y1 = relu(z[perm] @ W1_e + b1_e), bf16 ----------
// grid: (cols=32, rows=40)
__global__ __launch_bounds__(256) void k_gemm_e1(
    const unsigned short* __restrict__ z, const unsigned short* __restrict__ W1T,
    const float* __restrict__ eb1, const int* __restrict__ pad_off,
    const int* __restrict__ perm, unsigned short* __restrict__ Y1) {
    __shared__ unsigned short Als[12288], Bls[12288];
    const int tid = threadIdx.x, w = tid >> 6, l = tid & 63;
    const int col0 = blockIdx.x * 128, row0 = blockIdx.y * 128;
    if (row0 >= pad_off[E_]) return;
    int e = 0;
    while (row0 >= pad_off[e + 1]) e++;
    const int r0s = w * 16 + (l >> 2), r1s = 64 + w * 16 + (l >> 2);
    const int cs = ((l & 3) ^ ((l >> 3) & 3)) * 8;   // T2 pre-swizzled source slot
    int pr0 = perm[row0 + r0s]; if (pr0 < 0) pr0 = 0;
    int pr1 = perm[row0 + r1s]; if (pr1 < 0) pr1 = 0;
    const unsigned short* ap0 = z + (size_t)pr0 * D_ + cs;
    const unsigned short* ap1 = z + (size_t)pr1 * D_ + cs;
    const unsigned short* BTe = W1T + (size_t)e * F_ * D_;
    const unsigned short* bp0 = BTe + (size_t)(col0 + r0s) * D_ + cs;
    const unsigned short* bp1 = BTe + (size_t)(col0 + r1s) * D_ + cs;
    f32x4_t acc[4][4];
    gemm_core(ap0, ap1, bp0, bp1, D_, Als, Bls, acc);
    const float* b1e = eb1 + (size_t)e * F_;
    const int wm = (w >> 1) * 64, wn = (w & 1) * 64, fr = l & 15, fg4 = l >> 4;
    #pragma unroll
    for (int n = 0; n < 4; n++) {
        const int gcol = col0 + wn + n * 16 + fr;
        const float bias = b1e[gcol];
        #pragma unroll
        for (int m = 0; m < 4; m++)
            #pragma unroll
            for (int rr = 0; rr < 4; rr++) {
                const int grow = row0 + wm + m * 16 + fg4 * 4 + rr;
                Y1[(size_t)grow * F_ + gcol] = f2bf(fmaxf(acc[m][n][rr] + bias, 0.f));
            }
    }
}

// ---------- expert FFN GEMM 2, split-K=2: out += Y1 @ W2_e (atomic; out pre-init) ----------
// grid (rows=40, cols=8, kc=2)
__global__ __launch_bounds__(256) void k_gemm_e2(
    const unsigned short* __restrict__ Y1, const unsigned short* __restrict__ W2T,
    const int* __restrict__ pad_off, const int* __restrict__ perm,
    float* __restrict__ out) {
    __shared__ unsigned short Als[12288], Bls[12288];
    const int tid = threadIdx.x, w = tid >> 6, l = tid & 63;
    const int row0 = blockIdx.x * 128, col0 = blockIdx.y * 128;
    const int kc = blockIdx.z * 2048;
    if (row0 >= pad_off[E_]) return;
    int e = 0;
    while (row0 >= pad_off[e + 1]) e++;
    const int r0s = w * 16 + (l >> 2), r1s = 64 + w * 16 + (l >> 2);
    const int cs = ((l & 3) ^ ((l >> 3) & 3)) * 8;   // T2 pre-swizzled source slot
    const unsigned short* ap0 = Y1 + (size_t)(row0 + r0s) * F_ + kc + cs;
    const unsigned short* ap1 = Y1 + (size_t)(row0 + r1s) * F_ + kc + cs;
    const unsigned short* BTe = W2T + (size_t)e * D_ * F_;
    const unsigned short* bp0 = BTe + (size_t)(col0 + r0s) * F_ + kc + cs;
    const unsigned short* bp1 = BTe + (size_t)(col0 + r1s) * F_ + kc + cs;
    f32x4_t acc[4][4];
    gemm_core(ap0, ap1, bp0, bp1, 2048, Als, Bls, acc);
    const int wm = (w >> 1) * 64, wn = (w & 1) * 64, fr = l & 15, fg4 = l >> 4;
    #pragma unroll
    for (int n = 0; n < 4; n++) {
        const int gcol = col0 + wn + n * 16 + fr;
        #pragma unroll
        for (int m = 0; m < 4; m++)
            #pragma unroll
            for (int rr = 0; rr < 4; rr++) {
                const int grow = row0 + wm + m * 16 + fg4 * 4 + rr;
                const int rdst = perm[grow];
                if (rdst >= 0)
                    atomicAdd(&out[(size_t)rdst * D_ + gcol], acc[m][n][rr]);
            }
    }
}

extern "C" void kernel_launch(void* const* d_in, const int* in_sizes, int n_in,
                              void* d_out, int out_size, void* d_ws, size_t ws_size,
                              hipStream_t stream) {
    const float* x    = (const float*)d_in[0];
    const float* Wq   = (const float*)d_in[1];
    const float* bq   = (const float*)d_in[2];
    const float* Wk   = (const float*)d_in[3];
    const float* bk   = (const float*)d_in[4];
    const float* Wv   = (const float*)d_in[5];
    const float* bv   = (const float*)d_in[6];
    const float* Wo   = (const float*)d_in[7];
    const float* bo   = (const float*)d_in[8];
    const float* ln1g = (const float*)d_in[9];
    const float* ln1b = (const float*)d_in[10];
    const float* ln2g = (const float*)d_in[11];
    const float* ln2b = (const float*)d_in[12];
    const float* cent = (const float*)d_in[13];
    const float* egw  = (const float*)d_in[14];
    const float* ebw  = (const float*)d_in[15];
    const float* eW1  = (const float*)d_in[16];
    const float* eb1  = (const float*)d_in[17];
    const float* eW2  = (const float*)d_in[18];
    const float* eb2  = (const float*)d_in[19];
    float* out = (float*)d_out;

    char* W = (char*)d_ws;
    unsigned short* WqkvT = (unsigned short*)(W);                 //  6291456 B
    unsigned short* WoT   = (unsigned short*)(W + 6291456);       //  2097152 B
    unsigned short* Qb    = (unsigned short*)(W + 8388608);       //  8388608 B
    unsigned short* Kb    = (unsigned short*)(W + 16777216);      //  8388608 B
    unsigned short* Vb    = (unsigned short*)(W + 25165824);      //  8388608 B
    unsigned short* aout  = (unsigned short*)(W + 33554432);      //  8388608 B -> ends 41943040
    unsigned short* Y1    = (unsigned short*)(W);                 // 41943040 B (alias, all above dead)
    unsigned short* W1T   = (unsigned short*)(W + 41943040);      // 67108864 B
    unsigned short* W2T   = (unsigned short*)(W + 109051904);     // 67108864 B
    unsigned short* h1z   = (unsigned short*)(W + 176160768);     //  8388608 B (h1, later z)
    float*          x2    = (float*)(W + 184549376);              // 16777216 B -> ends 201326592
    unsigned short* Vt    = (unsigned short*)(W + 201326592);     //  8388608 B -> ends 209715200
    int*            assign= (int*)(W + 209715200);
    int*            perm  = (int*)(W + 209731584);
    int*            counts= (int*)(W + 209752064);
    int*            cursor= (int*)(W + 209752192);
    int*            pad_off=(int*)(W + 209752320);

    // weight transposes (fp32 -> bf16, B^T layout)
    k_transpose<<<dim3(32, 32, 1), 256, 0, stream>>>(Wq, WqkvT,               1024, 1024);
    k_transpose<<<dim3(32, 32, 1), 256, 0, stream>>>(Wk, WqkvT + 1024 * 1024, 1024, 1024);
    k_transpose<<<dim3(32, 32, 1), 256, 0, stream>>>(Wv, WqkvT + 2048 * 1024, 1024, 1024);
    k_transpose<<<dim3(32, 32, 1), 256, 0, stream>>>(Wo, WoT,                 1024, 1024);
    k_transpose<<<dim3(128, 32, 8), 256, 0, stream>>>(eW1, W1T, 1024, 4096);
    k_transpose<<<dim3(32, 128, 8), 256, 0, stream>>>(eW2, W2T, 4096, 1024);

    k_init<<<1, 256, 0, stream>>>(counts, cursor, perm);
    k_ln<<<N_, 256, 0, stream>>>(x, ln1g, ln1b, h1z);
    k_init_x2<<<N_, 256, 0, stream>>>(x, bo, x2);
    k_gemm_qkv<<<dim3(24, 32), 256, 0, stream>>>(h1z, WqkvT, bq, bk, bv, Qb, Kb, Vb);
    k_transpose_v<<<dim3(32, 16), 256, 0, stream>>>(Vb, Vt);
    k_attn<<<dim3(512), 256, 0, stream>>>(Qb, Kb, Vt, aout);
    k_gemm_o<<<dim3(32, 8, 2), 256, 0, stream>>>(aout, WoT, x2);
    k_ln2_gate<<<N_, 256, 0, stream>>>(x2, ln2g, ln2b, cent, egw, ebw, h1z, assign, counts);
    k_offsets<<<1, 64, 0, stream>>>(counts, pad_off);
    k_scatter<<<16, 256, 0, stream>>>(assign, pad_off, cursor, perm);
    k_init_out<<<N_, 256, 0, stream>>>(x2, eb2, assign, out);
    k_gemm_e1<<<dim3(32, 40), 256, 0, stream>>>(h1z, W1T, eb1, pad_off, perm, Y1);
    k_gemm_e2<<<dim3(40, 8, 2), 256, 0, stream>>>(Y1, W2T, pad_off, perm, out);
}

// Round 11
// 486.827 us; speedup vs baseline: 1.0080x; 1.0080x over previous
//
#include <hip/hip_runtime.h>
#include <hip/hip_bf16.h>
#include <math.h>

// Problem dims
#define T_ 2048
#define B_ 2
#define D_ 1024
#define H_ 16
#define F_ 4096
#define E_ 8
#define N_ 4096      // T_*B_ tokens, row r = t*B_ + b (memory order of x[T,B,D])
#define HD_ 64
#define PADROWS 5120 // N_ + E_*128 worst-case padded rows

typedef __attribute__((ext_vector_type(8))) short short8_t;
typedef __attribute__((ext_vector_type(4))) float f32x4_t;
typedef __attribute__((ext_vector_type(16))) float f32x16_t;
typedef __attribute__((ext_vector_type(4))) unsigned u32x4_t;

__device__ __forceinline__ unsigned short f2bf(float f) {
    union { float f; unsigned u; } a; a.f = f;
    unsigned r = a.u + 0x7FFFu + ((a.u >> 16) & 1u);   // RNE
    return (unsigned short)(r >> 16);
}

__device__ __forceinline__ unsigned cvtpk(float lo, float hi) {
    unsigned r;
    asm("v_cvt_pk_bf16_f32 %0, %1, %2" : "=v"(r) : "v"(lo), "v"(hi));
    return r;
}

__device__ __forceinline__ void glds16(const unsigned short* g, unsigned short* l) {
    __builtin_amdgcn_global_load_lds(
        (const __attribute__((address_space(1))) void*)g,
        (__attribute__((address_space(3))) void*)l, 16, 0, 0);
}

__device__ __forceinline__ void blockReduce2(float& a, float& b, float* sm) {
    #pragma unroll
    for (int m = 32; m; m >>= 1) { a += __shfl_xor(a, m); b += __shfl_xor(b, m); }
    const int w = threadIdx.x >> 6, l = threadIdx.x & 63;
    __syncthreads();
    if (l == 0) { sm[w] = a; sm[8 + w] = b; }
    __syncthreads();
    a = sm[0] + sm[1] + sm[2] + sm[3];
    b = sm[8] + sm[9] + sm[10] + sm[11];
}

// ---------- transpose + fp32->bf16 convert: out[c*R+r] = in[r*C+c] ----------
// Store phase vectorized: each thread emits one ushort4 (4 consecutive r's of one c-row).
__global__ __launch_bounds__(256) void k_transpose(const float* __restrict__ in,
                                                   unsigned short* __restrict__ out,
                                                   int R, int C) {
    __shared__ float tile[32][33];
    const int c0 = blockIdx.x * 32, r0 = blockIdx.y * 32;
    const size_t base = (size_t)blockIdx.z * R * C;
    in += base; out += base;
    const int tx = threadIdx.x & 31, ty = threadIdx.x >> 5; // ty 0..7
    #pragma unroll
    for (int i = 0; i < 32; i += 8)
        tile[ty + i][tx] = in[(size_t)(r0 + ty + i) * C + c0 + tx];
    __syncthreads();
    const int c = threadIdx.x >> 3, rq = (threadIdx.x & 7) * 4;
    ushort4 v;
    v.x = f2bf(tile[rq + 0][c]);
    v.y = f2bf(tile[rq + 1][c]);
    v.z = f2bf(tile[rq + 2][c]);
    v.w = f2bf(tile[rq + 3][c]);
    *(ushort4*)(out + (size_t)(c0 + c) * R + r0 + rq) = v;
}

// ---------- bf16 transpose for V: [32][T][HD] -> [32][HD][T] ----------
__global__ __launch_bounds__(256) void k_transpose_v(const unsigned short* __restrict__ in,
                                                     unsigned short* __restrict__ out) {
    const int bh = blockIdx.x;
    const int t0 = blockIdx.y * 128;
    const int tid = threadIdx.x;
    const int hd = tid & 63;
    const size_t ib = (size_t)bh * T_ * HD_;
    const size_t ob = (size_t)bh * HD_ * T_;
    for (int tb = tid >> 6; tb < 16; tb += 4) {
        const int t = t0 + tb * 8;
        short8_t v;
        #pragma unroll
        for (int k = 0; k < 8; ++k)
            v[k] = (short)in[ib + (size_t)(t + k) * HD_ + hd];   // coalesced 128B/lane-group
        *(short8_t*)(out + ob + (size_t)hd * T_ + t) = v;
    }
}

// ---------- LayerNorm (fp32 in, bf16 out), one block per row ----------
__global__ __launch_bounds__(256) void k_ln(const float* __restrict__ x,
                                            const float* __restrict__ g,
                                            const float* __restrict__ b,
                                            unsigned short* __restrict__ out) {
    __shared__ float sm[16];
    const int row = blockIdx.x, tid = threadIdx.x;
    const float4 v = *(const float4*)(x + (size_t)row * D_ + tid * 4);
    float s1 = v.x + v.y + v.z + v.w;
    float s2 = v.x * v.x + v.y * v.y + v.z * v.z + v.w * v.w;
    blockReduce2(s1, s2, sm);
    const float mean = s1 * (1.f / D_);
    const float inv  = rsqrtf(s2 * (1.f / D_) - mean * mean + 1e-5f);
    const float4 gg = *(const float4*)(g + tid * 4);
    const float4 bb = *(const float4*)(b + tid * 4);
    unsigned long long pk =
          (unsigned long long)f2bf((v.x - mean) * inv * gg.x + bb.x)
        | ((unsigned long long)f2bf((v.y - mean) * inv * gg.y + bb.y) << 16)
        | ((unsigned long long)f2bf((v.z - mean) * inv * gg.z + bb.z) << 32)
        | ((unsigned long long)f2bf((v.w - mean) * inv * gg.w + bb.w) << 48);
    *(unsigned long long*)(out + (size_t)row * D_ + tid * 4) = pk;
}

// ---------- init kernels for split-K accumulation ----------
__global__ __launch_bounds__(256) void k_init_x2(const float* __restrict__ x,
                                                 const float* __restrict__ bo,
                                                 float* __restrict__ x2) {
    const int row = blockIdx.x, tid = threadIdx.x;
    const size_t idx = (size_t)row * D_ + tid * 4;
    const float4 v = *(const float4*)(x + idx);
    const float4 b = *(const float4*)(bo + tid * 4);
    float4 o; o.x = v.x + b.x; o.y = v.y + b.y; o.z = v.z + b.z; o.w = v.w + b.w;
    *(float4*)(x2 + idx) = o;
}

__global__ __launch_bounds__(256) void k_init_out(const float* __restrict__ x2u,
                                                  const float* __restrict__ eb2,
                                                  const int* __restrict__ assign,
                                                  float* __restrict__ out) {
    const int row = blockIdx.x, tid = threadIdx.x;
    const int e = assign[row];
    const size_t idx = (size_t)row * D_ + tid * 4;
    const float4 v = *(const float4*)(x2u + idx);
    const float4 b = *(const float4*)(eb2 + (size_t)e * D_ + tid * 4);
    float4 o; o.x = v.x + b.x; o.y = v.y + b.y; o.z = v.z + b.z; o.w = v.w + b.w;
    *(float4*)(out + idx) = o;
}

// ---------- shared 128x128xK bf16 GEMM core, 3-buffer depth-2 pipeline (T3+T4+T2) ----------
__device__ __forceinline__ void gemm_core(const unsigned short* ap0, const unsigned short* ap1,
                                          const unsigned short* bp0, const unsigned short* bp1,
                                          int K, unsigned short* Als, unsigned short* Bls,
                                          f32x4_t (&acc)[4][4]) {
    const int tid = threadIdx.x, w = tid >> 6, l = tid & 63;
    const int wm = (w >> 1) * 64, wn = (w & 1) * 64;
    const int fr = l & 15, fg = (l >> 4) * 8;
    const int fgs = fg ^ (((fr >> 1) & 3) << 3);   // swizzled k-slot for this lane's rows
    f32x4_t z4 = {0.f, 0.f, 0.f, 0.f};
    #pragma unroll
    for (int m = 0; m < 4; m++)
        #pragma unroll
        for (int n = 0; n < 4; n++) acc[m][n] = z4;
    // prologue: stage tiles 0 and 1 into buffers 0 and 1
    glds16(ap0, Als + w * 512);
    glds16(ap1, Als + (w + 4) * 512);
    glds16(bp0, Bls + w * 512);
    glds16(bp1, Bls + (w + 4) * 512);
    ap0 += 32; ap1 += 32; bp0 += 32; bp1 += 32;
    glds16(ap0, Als + 4096 + w * 512);
    glds16(ap1, Als + 4096 + (w + 4) * 512);
    glds16(bp0, Bls + 4096 + w * 512);
    glds16(bp1, Bls + 4096 + (w + 4) * 512);
    ap0 += 32; ap1 += 32; bp0 += 32; bp1 += 32;
    unsigned c0 = 0, c1 = 4096, c2 = 8192;   // compute / in-flight / issue targets
    const int nk = K >> 5;
    for (int kt = 0; kt < nk; ++kt) {
        if (kt < nk - 1) asm volatile("s_waitcnt vmcnt(4)" ::: "memory");
        else             asm volatile("s_waitcnt vmcnt(0)" ::: "memory");
        __builtin_amdgcn_s_barrier();
        __builtin_amdgcn_sched_barrier(0);
        short8_t a[4], b[4];
        #pragma unroll
        for (int m = 0; m < 4; m++) a[m] = *(const short8_t*)(Als + c0 + (wm + m * 16 + fr) * 32 + fgs);
        #pragma unroll
        for (int n = 0; n < 4; n++) b[n] = *(const short8_t*)(Bls + c0 + (wn + n * 16 + fr) * 32 + fgs);
        #pragma unroll
        for (int m = 0; m < 4; m++)
            #pragma unroll
            for (int n = 0; n < 4; n++)
                acc[m][n] = __builtin_amdgcn_mfma_f32_16x16x32_bf16(a[m], b[n], acc[m][n], 0, 0, 0);
        if (kt + 2 < nk) {                    // issue tile k+2 into the retired buffer
            glds16(ap0, Als + c2 + w * 512);
            glds16(ap1, Als + c2 + (w + 4) * 512);
            glds16(bp0, Bls + c2 + w * 512);
            glds16(bp1, Bls + c2 + (w + 4) * 512);
            ap0 += 32; ap1 += 32; bp0 += 32; bp1 += 32;
        }
        const unsigned t = c0; c0 = c1; c1 = c2; c2 = t;
    }
}

// ---------- GEMM: h1 @ [Wq|Wk|Wv] + bias, scale q, scatter into [B,H,T,HD] ----------
__global__ __launch_bounds__(256) void k_gemm_qkv(
    const unsigned short* __restrict__ A, const unsigned short* __restrict__ BT,
    const float* __restrict__ bq, const float* __restrict__ bk, const float* __restrict__ bv,
    unsigned short* __restrict__ Qb, unsigned short* __restrict__ Kb, unsigned short* __restrict__ Vb) {
    __shared__ unsigned short Als[12288], Bls[12288];
    const int tid = threadIdx.x, w = tid >> 6, l = tid & 63;
    const int col0 = blockIdx.x * 128, row0 = blockIdx.y * 128;
    const int r0s = w * 16 + (l >> 2), r1s = 64 + w * 16 + (l >> 2);
    const int cs = ((l & 3) ^ ((l >> 3) & 3)) * 8;   // T2 pre-swizzled source slot
    const unsigned short* ap0 = A + (size_t)(row0 + r0s) * D_ + cs;
    const unsigned short* ap1 = A + (size_t)(row0 + r1s) * D_ + cs;
    const unsigned short* bp0 = BT + (size_t)(col0 + r0s) * D_ + cs;
    const unsigned short* bp1 = BT + (size_t)(col0 + r1s) * D_ + cs;
    f32x4_t acc[4][4];
    gemm_core(ap0, ap1, bp0, bp1, D_, Als, Bls, acc);
    const int wm = (w >> 1) * 64, wn = (w & 1) * 64, fr = l & 15, fg4 = l >> 4;
    #pragma unroll
    for (int n = 0; n < 4; n++) {
        const int gcol = col0 + wn + n * 16 + fr;
        const int which = gcol >> 10, dc = gcol & 1023;
        const float bias = which == 0 ? bq[dc] : (which == 1 ? bk[dc] : bv[dc]);
        unsigned short* dst = which == 0 ? Qb : (which == 1 ? Kb : Vb);
        const int hh = dc >> 6, hd = dc & 63;
        #pragma unroll
        for (int m = 0; m < 4; m++)
            #pragma unroll
            for (int rr = 0; rr < 4; rr++) {
                const int grow = row0 + wm + m * 16 + fg4 * 4 + rr;
                float v = acc[m][n][rr] + bias;
                if (which == 0) v *= 0.1803368801111204f; // HD^-0.5 * log2(e)
                const int t = grow >> 1, bb = grow & 1;
                dst[((size_t)(bb * H_ + hh) * T_ + t) * HD_ + hd] = f2bf(v);
            }
    }
}

// ---------- causal flash attention v6: swapped QK^T + 3-buffer depth-2 counted vmcnt ----------
__global__ __launch_bounds__(256) void k_attn(const unsigned short* __restrict__ Qb,
                                              const unsigned short* __restrict__ Kb,
                                              const unsigned short* __restrict__ Vt,
                                              unsigned short* __restrict__ aout) {
    __shared__ unsigned short Kl[3 * 4096];  // 3 buffers [64 kv][64 hd], swizzled content
    __shared__ unsigned short Vl[3 * 4096];  // 3 buffers [64 hd][64 kv], swizzled content
    const int id = blockIdx.x;
    const int qt = (id < 256) ? (15 - (id & 15)) : (id & 15);
    const int bh = (id >> 4) & 31;
    const int tid = threadIdx.x, w = tid >> 6, l = tid & 63;
    const int q5 = l & 31, hi = l >> 5, l7 = l & 7;
    const int row0 = w * 8 + (l >> 3);             // staging row (0..31)
    const int swz = ((l & 7) ^ (l >> 3)) * 8;      // pre-swizzled source column (elements)
    const size_t base = (size_t)bh * T_ * HD_;
    const unsigned short* Qp = Qb + base;
    const unsigned short* kps = Kb + base + (size_t)row0 * HD_ + swz;
    const unsigned short* vps = Vt + base + (size_t)row0 * T_ + swz;  // [HD][T]
    const int qw0 = qt * 128 + w * 32;
    const int q = qw0 + q5;

    short8_t aq[4];
    #pragma unroll
    for (int khd = 0; khd < 4; ++khd)
        aq[khd] = *(const short8_t*)(Qp + (size_t)q * HD_ + khd * 16 + hi * 8);

    f32x16_t accO0, accO1;
    #pragma unroll
    for (int i = 0; i < 16; ++i) { accO0[i] = 0.f; accO1[i] = 0.f; }
    float mrun = -1e30f, lrun = 0.f;

    const int niter = (qt + 1) * 2;   // always >= 2

#define STAGE_KV(t, b) { \
    const size_t ko = (size_t)(t) * 64 * HD_; const int vo = (t) * 64; \
    glds16(kps + ko,            Kl + (b) + w * 512); \
    glds16(kps + ko + 32 * HD_, Kl + (b) + 2048 + w * 512); \
    glds16(vps + vo,            Vl + (b) + w * 512); \
    glds16(vps + vo + 32 * T_,  Vl + (b) + 2048 + w * 512); }

    STAGE_KV(0, 0);
    STAGE_KV(1, 4096);
    unsigned c0 = 0, c1 = 4096, c2 = 8192;

    for (int it = 0; it < niter; ++it) {
        if (it < niter - 1) asm volatile("s_waitcnt vmcnt(4)" ::: "memory");
        else                asm volatile("s_waitcnt vmcnt(0)" ::: "memory");
        __builtin_amdgcn_s_barrier();
        __builtin_amdgcn_sched_barrier(0);
        const int s0 = it * 64;
        if (s0 <= qw0 + 31) {
            const unsigned short* KT = Kl + c0;
            const unsigned short* VT = Vl + c0;

            f32x16_t st0, st1;
            #pragma unroll
            for (int i = 0; i < 16; ++i) { st0[i] = 0.f; st1[i] = 0.f; }
            #pragma unroll
            for (int khd = 0; khd < 4; ++khd) {
                const int cb = (khd * 16 + hi * 8) ^ (l7 * 8);
                const short8_t k0 = *(const short8_t*)(KT + q5 * 64 + cb);
                const short8_t k1 = *(const short8_t*)(KT + (32 + q5) * 64 + cb);
                st0 = __builtin_amdgcn_mfma_f32_32x32x16_bf16(k0, aq[khd], st0, 0, 0, 0);
                st1 = __builtin_amdgcn_mfma_f32_32x32x16_bf16(k1, aq[khd], st1, 0, 0, 0);
            }

            const bool domask = (s0 + 63 > qw0);
            float pmax = -3e38f;
            #pragma unroll
            for (int r = 0; r < 16; ++r) {
                float v0 = st0[r], v1 = st1[r];
                if (domask) {
                    const int kv0 = s0 + (r & 3) + 8 * (r >> 2) + 4 * hi;
                    if (kv0 > q)      v0 = -1e30f;
                    if (kv0 + 32 > q) v1 = -1e30f;
                }
                st0[r] = v0; st1[r] = v1;
                pmax = fmaxf(pmax, fmaxf(v0, v1));
            }
            pmax = fmaxf(pmax, __shfl_xor(pmax, 32));
            const float mnew = fmaxf(mrun, pmax);
            const float scl = exp2f(mrun - mnew);
            float pt0[16], pt1[16];
            float rs = 0.f;
            #pragma unroll
            for (int r = 0; r < 16; ++r) {
                pt0[r] = exp2f(st0[r] - mnew);
                pt1[r] = exp2f(st1[r] - mnew);
                rs += pt0[r] + pt1[r];
            }
            rs += __shfl_xor(rs, 32);
            lrun = lrun * scl + rs;
            mrun = mnew;
            #pragma unroll
            for (int i = 0; i < 16; ++i) { accO0[i] *= scl; accO1[i] *= scl; }

            unsigned Wp[2][4][2];
            #pragma unroll
            for (int b = 0; b < 4; ++b) {
                Wp[0][b][0] = cvtpk(pt0[4 * b + 0], pt0[4 * b + 1]);
                Wp[0][b][1] = cvtpk(pt0[4 * b + 2], pt0[4 * b + 3]);
                Wp[1][b][0] = cvtpk(pt1[4 * b + 0], pt1[4 * b + 1]);
                Wp[1][b][1] = cvtpk(pt1[4 * b + 2], pt1[4 * b + 3]);
            }

            #pragma unroll
            for (int ks = 0; ks < 4; ++ks) {
                const int t = ks >> 1, b0 = (ks & 1) * 2;
                const unsigned ownA0 = Wp[t][b0][0],     ownA1 = Wp[t][b0][1];
                const unsigned ownB0 = Wp[t][b0 + 1][0], ownB1 = Wp[t][b0 + 1][1];
                const unsigned send0 = hi ? ownA0 : ownB0;
                const unsigned send1 = hi ? ownA1 : ownB1;
                const unsigned recv0 = __shfl_xor(send0, 32);
                const unsigned recv1 = __shfl_xor(send1, 32);
                u32x4_t wds;
                wds[0] = hi ? recv0 : ownA0;
                wds[1] = hi ? recv1 : ownA1;
                wds[2] = hi ? ownB0 : recv0;
                wds[3] = hi ? ownB1 : recv1;
                const short8_t pfrag = __builtin_bit_cast(short8_t, wds);
                const int cb = (ks * 16 + hi * 8) ^ (l7 * 8);
                const short8_t v0 = *(const short8_t*)(VT + q5 * 64 + cb);
                const short8_t v1 = *(const short8_t*)(VT + (32 + q5) * 64 + cb);
                accO0 = __builtin_amdgcn_mfma_f32_32x32x16_bf16(v0, pfrag, accO0, 0, 0, 0);
                accO1 = __builtin_amdgcn_mfma_f32_32x32x16_bf16(v1, pfrag, accO1, 0, 0, 0);
            }
        }
        if (it + 2 < niter) STAGE_KV(it + 2, c2);
        const unsigned tb = c0; c0 = c1; c1 = c2; c2 = tb;
    }
#undef STAGE_KV

    const float linv = 1.f / lrun;
    const int bidx = bh >> 4, hidx = bh & 15;
    unsigned short* orow = aout + (size_t)(q * B_ + bidx) * D_ + hidx * 64;
    #pragma unroll
    for (int g = 0; g < 4; ++g) {
        const int hd0 = 8 * g + 4 * hi;
        unsigned long long pk0 =
              (unsigned long long)f2bf(accO0[4 * g + 0] * linv)
            | ((unsigned long long)f2bf(accO0[4 * g + 1] * linv) << 16)
            | ((unsigned long long)f2bf(accO0[4 * g + 2] * linv) << 32)
            | ((unsigned long long)f2bf(accO0[4 * g + 3] * linv) << 48);
        *(unsigned long long*)(orow + hd0) = pk0;
        unsigned long long pk1 =
              (unsigned long long)f2bf(accO1[4 * g + 0] * linv)
            | ((unsigned long long)f2bf(accO1[4 * g + 1] * linv) << 16)
            | ((unsigned long long)f2bf(accO1[4 * g + 2] * linv) << 32)
            | ((unsigned long long)f2bf(accO1[4 * g + 3] * linv) << 48);
        *(unsigned long long*)(orow + 32 + hd0) = pk1;
    }
}

// ---------- O-projection, split-K=2: x2 += aout @ Wo (atomic; x2 pre-init with x+bo) ----------
__global__ __launch_bounds__(256) void k_gemm_o(
    const unsigned short* __restrict__ A, const unsigned short* __restrict__ BT,
    float* __restrict__ x2) {
    __shared__ unsigned short Als[12288], Bls[12288];
    const int tid = threadIdx.x, w = tid >> 6, l = tid & 63;
    const int row0 = blockIdx.x * 128, col0 = blockIdx.y * 128;
    const int kc = blockIdx.z * 512;
    const int r0s = w * 16 + (l >> 2), r1s = 64 + w * 16 + (l >> 2);
    const int cs = ((l & 3) ^ ((l >> 3) & 3)) * 8;   // T2 pre-swizzled source slot
    const unsigned short* ap0 = A + (size_t)(row0 + r0s) * D_ + kc + cs;
    const unsigned short* ap1 = A + (size_t)(row0 + r1s) * D_ + kc + cs;
    const unsigned short* bp0 = BT + (size_t)(col0 + r0s) * D_ + kc + cs;
    const unsigned short* bp1 = BT + (size_t)(col0 + r1s) * D_ + kc + cs;
    f32x4_t acc[4][4];
    gemm_core(ap0, ap1, bp0, bp1, 512, Als, Bls, acc);
    const int wm = (w >> 1) * 64, wn = (w & 1) * 64, fr = l & 15, fg4 = l >> 4;
    #pragma unroll
    for (int n = 0; n < 4; n++) {
        const int gcol = col0 + wn + n * 16 + fr;
        #pragma unroll
        for (int m = 0; m < 4; m++)
            #pragma unroll
            for (int rr = 0; rr < 4; rr++) {
                const int grow = row0 + wm + m * 16 + fg4 * 4 + rr;
                atomicAdd(&x2[(size_t)grow * D_ + gcol], acc[m][n][rr]);
            }
    }
}

// ---------- LN2 + gating + expert-LN; x2 <- x2 + u (in place) ----------
__global__ __launch_bounds__(256) void k_ln2_gate(
    float* __restrict__ x2, const float* __restrict__ g2, const float* __restrict__ b2,
    const float* __restrict__ cent, const float* __restrict__ eg, const float* __restrict__ eb,
    unsigned short* __restrict__ z, int* __restrict__ assign, int* __restrict__ counts) {
    __shared__ float sm[48];
    const int row = blockIdx.x, tid = threadIdx.x;
    const int w = tid >> 6, l = tid & 63;
    float* xr = x2 + (size_t)row * D_;
    const float4 v = *(const float4*)(xr + tid * 4);
    float s1 = v.x + v.y + v.z + v.w;
    float s2 = v.x * v.x + v.y * v.y + v.z * v.z + v.w * v.w;
    blockReduce2(s1, s2, sm);
    const float mean = s1 * (1.f / D_);
    const float inv  = rsqrtf(s2 * (1.f / D_) - mean * mean + 1e-5f);
    const float4 gg = *(const float4*)(g2 + tid * 4), bb = *(const float4*)(b2 + tid * 4);
    float4 u;
    u.x = (v.x - mean) * inv * gg.x + bb.x;
    u.y = (v.y - mean) * inv * gg.y + bb.y;
    u.z = (v.z - mean) * inv * gg.z + bb.z;
    u.w = (v.w - mean) * inv * gg.w + bb.w;
    float p[E_];
    #pragma unroll
    for (int e = 0; e < E_; e++) {
        const float4 c = *(const float4*)(cent + (size_t)e * D_ + tid * 4);
        p[e] = u.x * c.x + u.y * c.y + u.z * c.z + u.w * c.w;
    }
    #pragma unroll
    for (int m = 32; m; m >>= 1)
        #pragma unroll
        for (int e = 0; e < E_; e++) p[e] += __shfl_xor(p[e], m);
    __syncthreads();
    if (l == 0) {
        #pragma unroll
        for (int e = 0; e < E_; e++) sm[16 + e * 4 + w] = p[e];
    }
    __syncthreads();
    int best = 0; float bl = -1e30f;
    #pragma unroll
    for (int e = 0; e < E_; e++) {
        const float le = sm[16 + e * 4] + sm[16 + e * 4 + 1] + sm[16 + e * 4 + 2] + sm[16 + e * 4 + 3];
        if (le > bl) { bl = le; best = e; }
    }
    float t1 = u.x + u.y + u.z + u.w;
    float t2 = u.x * u.x + u.y * u.y + u.z * u.z + u.w * u.w;
    blockReduce2(t1, t2, sm);
    const float m2   = t1 * (1.f / D_);
    const float inv2 = rsqrtf(t2 * (1.f / D_) - m2 * m2 + 1e-5f);
    const float4 egv = *(const float4*)(eg + (size_t)best * D_ + tid * 4);
    const float4 ebv = *(const float4*)(eb + (size_t)best * D_ + tid * 4);
    unsigned long long pk =
          (unsigned long long)f2bf((u.x - m2) * inv2 * egv.x + ebv.x)
        | ((unsigned long long)f2bf((u.y - m2) * inv2 * egv.y + ebv.y) << 16)
        | ((unsigned long long)f2bf((u.z - m2) * inv2 * egv.z + ebv.z) << 32)
        | ((unsigned long long)f2bf((u.w - m2) * inv2 * egv.w + ebv.w) << 48);
    *(unsigned long long*)(z + (size_t)row * D_ + tid * 4) = pk;
    float4 xu; xu.x = v.x + u.x; xu.y = v.y + u.y; xu.z = v.z + u.z; xu.w = v.w + u.w;
    *(float4*)(xr + tid * 4) = xu;
    if (tid == 0) { assign[row] = best; atomicAdd(&counts[best], 1); }
}

// ---------- routing bookkeeping ----------
__global__ void k_init(int* counts, int* cursor, int* perm) {
    const int t = threadIdx.x;
    if (t < E_) { counts[t] = 0; cursor[t] = 0; }
    for (int i = t; i < PADROWS; i += 256) perm[i] = -1;
}

__global__ void k_offsets(const int* counts, int* pad_off) {
    if (threadIdx.x == 0) {
        int o = 0; pad_off[0] = 0;
        for (int e = 0; e < E_; e++) { o += ((counts[e] + 127) >> 7) << 7; pad_off[e + 1] = o; }
    }
}

__global__ void k_scatter(const int* assign, const int* pad_off, int* cursor, int* perm) {
    const int r = blockIdx.x * 256 + threadIdx.x;
    if (r >= N_) return;
    const int e = assign[r];
    const int pos = pad_off[e] + atomicAdd(&cursor[e], 1);
    perm[pos] = r;
}

// ---------- expert FFN GEMM 1: Y1 = relu(z[perm] @ W1_e + b1_e), bf16 ----------
// grid: (cols=32, rows=40)
__global__ __launch_bounds__(256) void k_gemm_e1(
    const unsigned short* __restrict__ z, const unsigned short* __restrict__ W1T,
    const float* __restrict__ eb1, const int* __restrict__ pad_off,
    const int* __restrict__ perm, unsigned short* __restrict__ Y1) {
    __shared__ unsigned short Als[12288], Bls[12288];
    const int tid = threadIdx.x, w = tid >> 6, l = tid & 63;
    const int col0 = blockIdx.x * 128, row0 = blockIdx.y * 128;
    if (row0 >= pad_off[E_]) return;
    int e = 0;
    while (row0 >= pad_off[e + 1]) e++;
    const int r0s = w * 16 + (l >> 2), r1s = 64 + w * 16 + (l >> 2);
    const int cs = ((l & 3) ^ ((l >> 3) & 3)) * 8;   // T2 pre-swizzled source slot
    int pr0 = perm[row0 + r0s]; if (pr0 < 0) pr0 = 0;
    int pr1 = perm[row0 + r1s]; if (pr1 < 0) pr1 = 0;
    const unsigned short* ap0 = z + (size_t)pr0 * D_ + cs;
    const unsigned short* ap1 = z + (size_t)pr1 * D_ + cs;
    const unsigned short* BTe = W1T + (size_t)e * F_ * D_;
    const unsigned short* bp0 = BTe + (size_t)(col0 + r0s) * D_ + cs;
    const unsigned short* bp1 = BTe + (size_t)(col0 + r1s) * D_ + cs;
    f32x4_t acc[4][4];
    gemm_core(ap0, ap1, bp0, bp1, D_, Als, Bls, acc);
    const float* b1e = eb1 + (size_t)e * F_;
    const int wm = (w >> 1) * 64, wn = (w & 1) * 64, fr = l & 15, fg4 = l >> 4;
    #pragma unroll
    for (int n = 0; n < 4; n++) {
        const int gcol = col0 + wn + n * 16 + fr;
        const float bias = b1e[gcol];
        #pragma unroll
        for (int m = 0; m < 4; m++)
            #pragma unroll
            for (int rr = 0; rr < 4; rr++) {
                const int grow = row0 + wm + m * 16 + fg4 * 4 + rr;
                Y1[(size_t)grow * F_ + gcol] = f2bf(fmaxf(acc[m][n][rr] + bias, 0.f));
            }
    }
}

// ---------- expert FFN GEMM 2, split-K=2: out += Y1 @ W2_e (atomic; out pre-init) ----------
// grid (rows=40, cols=8, kc=2)
__global__ __launch_bounds__(256) void k_gemm_e2(
    const unsigned short* __restrict__ Y1, const unsigned short* __restrict__ W2T,
    const int* __restrict__ pad_off, const int* __restrict__ perm,
    float* __restrict__ out) {
    __shared__ unsigned short Als[12288], Bls[12288];
    const int tid = threadIdx.x, w = tid >> 6, l = tid & 63;
    const int row0 = blockIdx.x * 128, col0 = blockIdx.y * 128;
    const int kc = blockIdx.z * 2048;
    if (row0 >= pad_off[E_]) return;
    int e = 0;
    while (row0 >= pad_off[e + 1]) e++;
    const int r0s = w * 16 + (l >> 2), r1s = 64 + w * 16 + (l >> 2);
    const int cs = ((l & 3) ^ ((l >> 3) & 3)) * 8;   // T2 pre-swizzled source slot
    const unsigned short* ap0 = Y1 + (size_t)(row0 + r0s) * F_ + kc + cs;
    const unsigned short* ap1 = Y1 + (size_t)(row0 + r1s) * F_ + kc + cs;
    const unsigned short* BTe = W2T + (size_t)e * D_ * F_;
    const unsigned short* bp0 = BTe + (size_t)(col0 + r0s) * F_ + kc + cs;
    const unsigned short* bp1 = BTe + (size_t)(col0 + r1s) * F_ + kc + cs;
    f32x4_t acc[4][4];
    gemm_core(ap0, ap1, bp0, bp1, 2048, Als, Bls, acc);
    const int wm = (w >> 1) * 64, wn = (w & 1) * 64, fr = l & 15, fg4 = l >> 4;
    #pragma unroll
    for (int n = 0; n < 4; n++) {
        const int gcol = col0 + wn + n * 16 + fr;
        #pragma unroll
        for (int m = 0; m < 4; m++)
            #pragma unroll
            for (int rr = 0; rr < 4; rr++) {
                const int grow = row0 + wm + m * 16 + fg4 * 4 + rr;
                const int rdst = perm[grow];
                if (rdst >= 0)
                    atomicAdd(&out[(size_t)rdst * D_ + gcol], acc[m][n][rr]);
            }
    }
}

extern "C" void kernel_launch(void* const* d_in, const int* in_sizes, int n_in,
                              void* d_out, int out_size, void* d_ws, size_t ws_size,
                              hipStream_t stream) {
    const float* x    = (const float*)d_in[0];
    const float* Wq   = (const float*)d_in[1];
    const float* bq   = (const float*)d_in[2];
    const float* Wk   = (const float*)d_in[3];
    const float* bk   = (const float*)d_in[4];
    const float* Wv   = (const float*)d_in[5];
    const float* bv   = (const float*)d_in[6];
    const float* Wo   = (const float*)d_in[7];
    const float* bo   = (const float*)d_in[8];
    const float* ln1g = (const float*)d_in[9];
    const float* ln1b = (const float*)d_in[10];
    const float* ln2g = (const float*)d_in[11];
    const float* ln2b = (const float*)d_in[12];
    const float* cent = (const float*)d_in[13];
    const float* egw  = (const float*)d_in[14];
    const float* ebw  = (const float*)d_in[15];
    const float* eW1  = (const float*)d_in[16];
    const float* eb1  = (const float*)d_in[17];
    const float* eW2  = (const float*)d_in[18];
    const float* eb2  = (const float*)d_in[19];
    float* out = (float*)d_out;

    char* W = (char*)d_ws;
    unsigned short* WqkvT = (unsigned short*)(W);                 //  6291456 B
    unsigned short* WoT   = (unsigned short*)(W + 6291456);       //  2097152 B
    unsigned short* Qb    = (unsigned short*)(W + 8388608);       //  8388608 B
    unsigned short* Kb    = (unsigned short*)(W + 16777216);      //  8388608 B
    unsigned short* Vb    = (unsigned short*)(W + 25165824);      //  8388608 B
    unsigned short* aout  = (unsigned short*)(W + 33554432);      //  8388608 B -> ends 41943040
    unsigned short* Y1    = (unsigned short*)(W);                 // 41943040 B (alias, all above dead)
    unsigned short* W1T   = (unsigned short*)(W + 41943040);      // 67108864 B
    unsigned short* W2T   = (unsigned short*)(W + 109051904);     // 67108864 B
    unsigned short* h1z   = (unsigned short*)(W + 176160768);     //  8388608 B (h1, later z)
    float*          x2    = (float*)(W + 184549376);              // 16777216 B -> ends 201326592
    unsigned short* Vt    = (unsigned short*)(W + 201326592);     //  8388608 B -> ends 209715200
    int*            assign= (int*)(W + 209715200);
    int*            perm  = (int*)(W + 209731584);
    int*            counts= (int*)(W + 209752064);
    int*            cursor= (int*)(W + 209752192);
    int*            pad_off=(int*)(W + 209752320);

    // weight transposes (fp32 -> bf16, B^T layout)
    k_transpose<<<dim3(32, 32, 1), 256, 0, stream>>>(Wq, WqkvT,               1024, 1024);
    k_transpose<<<dim3(32, 32, 1), 256, 0, stream>>>(Wk, WqkvT + 1024 * 1024, 1024, 1024);
    k_transpose<<<dim3(32, 32, 1), 256, 0, stream>>>(Wv, WqkvT + 2048 * 1024, 1024, 1024);
    k_transpose<<<dim3(32, 32, 1), 256, 0, stream>>>(Wo, WoT,                 1024, 1024);
    k_transpose<<<dim3(128, 32, 8), 256, 0, stream>>>(eW1, W1T, 1024, 4096);
    k_transpose<<<dim3(32, 128, 8), 256, 0, stream>>>(eW2, W2T, 4096, 1024);

    k_init<<<1, 256, 0, stream>>>(counts, cursor, perm);
    k_ln<<<N_, 256, 0, stream>>>(x, ln1g, ln1b, h1z);
    k_init_x2<<<N_, 256, 0, stream>>>(x, bo, x2);
    k_gemm_qkv<<<dim3(24, 32), 256, 0, stream>>>(h1z, WqkvT, bq, bk, bv, Qb, Kb, Vb);
    k_transpose_v<<<dim3(32, 16), 256, 0, stream>>>(Vb, Vt);
    k_attn<<<dim3(512), 256, 0, stream>>>(Qb, Kb, Vt, aout);
    k_gemm_o<<<dim3(32, 8, 2), 256, 0, stream>>>(aout, WoT, x2);
    k_ln2_gate<<<N_, 256, 0, stream>>>(x2, ln2g, ln2b, cent, egw, ebw, h1z, assign, counts);
    k_offsets<<<1, 64, 0, stream>>>(counts, pad_off);
    k_scatter<<<16, 256, 0, stream>>>(assign, pad_off, cursor, perm);
    k_init_out<<<N_, 256, 0, stream>>>(x2, eb2, assign, out);
    k_gemm_e1<<<dim3(32, 40), 256, 0, stream>>>(h1z, W1T, eb1, pad_off, perm, Y1);
    k_gemm_e2<<<dim3(40, 8, 2), 256, 0, stream>>>(Y1, W2T, pad_off, perm, out);
}

// Round 12
// 481.344 us; speedup vs baseline: 1.0195x; 1.0114x over previous
//
#include <hip/hip_runtime.h>
#include <hip/hip_bf16.h>
#include <math.h>

// Problem dims
#define T_ 2048
#define B_ 2
#define D_ 1024
#define H_ 16
#define F_ 4096
#define E_ 8
#define N_ 4096      // T_*B_ tokens, row r = t*B_ + b (memory order of x[T,B,D])
#define HD_ 64
#define PADROWS 5120 // N_ + E_*128 worst-case padded rows

typedef __attribute__((ext_vector_type(8))) short short8_t;
typedef __attribute__((ext_vector_type(4))) float f32x4_t;
typedef __attribute__((ext_vector_type(16))) float f32x16_t;
typedef __attribute__((ext_vector_type(4))) unsigned u32x4_t;

__device__ __forceinline__ unsigned short f2bf(float f) {
    union { float f; unsigned u; } a; a.f = f;
    unsigned r = a.u + 0x7FFFu + ((a.u >> 16) & 1u);   // RNE
    return (unsigned short)(r >> 16);
}

__device__ __forceinline__ unsigned cvtpk(float lo, float hi) {
    unsigned r;
    asm("v_cvt_pk_bf16_f32 %0, %1, %2" : "=v"(r) : "v"(lo), "v"(hi));
    return r;
}

__device__ __forceinline__ void glds16(const unsigned short* g, unsigned short* l) {
    __builtin_amdgcn_global_load_lds(
        (const __attribute__((address_space(1))) void*)g,
        (__attribute__((address_space(3))) void*)l, 16, 0, 0);
}

__device__ __forceinline__ void blockReduce2(float& a, float& b, float* sm) {
    #pragma unroll
    for (int m = 32; m; m >>= 1) { a += __shfl_xor(a, m); b += __shfl_xor(b, m); }
    const int w = threadIdx.x >> 6, l = threadIdx.x & 63;
    __syncthreads();
    if (l == 0) { sm[w] = a; sm[8 + w] = b; }
    __syncthreads();
    a = sm[0] + sm[1] + sm[2] + sm[3];
    b = sm[8] + sm[9] + sm[10] + sm[11];
}

// ---------- fused transpose of the four 1024x1024 fp32 weights -> bf16 B^T ----------
__global__ __launch_bounds__(256) void k_transpose4(
    const float* __restrict__ Wq, const float* __restrict__ Wk,
    const float* __restrict__ Wv, const float* __restrict__ Wo,
    unsigned short* __restrict__ WqkvT, unsigned short* __restrict__ WoT) {
    __shared__ float tile[32][33];
    const int zi = blockIdx.z;
    const float* in = zi == 0 ? Wq : (zi == 1 ? Wk : (zi == 2 ? Wv : Wo));
    unsigned short* out = zi == 3 ? WoT : (WqkvT + (size_t)zi * 1024 * 1024);
    const int c0 = blockIdx.x * 32, r0 = blockIdx.y * 32;
    const int tx = threadIdx.x & 31, ty = threadIdx.x >> 5;
    #pragma unroll
    for (int i = 0; i < 32; i += 8)
        tile[ty + i][tx] = in[(size_t)(r0 + ty + i) * 1024 + c0 + tx];
    __syncthreads();
    const int c = threadIdx.x >> 3, rq = (threadIdx.x & 7) * 4;
    ushort4 v;
    v.x = f2bf(tile[rq + 0][c]);
    v.y = f2bf(tile[rq + 1][c]);
    v.z = f2bf(tile[rq + 2][c]);
    v.w = f2bf(tile[rq + 3][c]);
    *(ushort4*)(out + (size_t)(c0 + c) * 1024 + r0 + rq) = v;
}

// ---------- transpose + fp32->bf16 convert (expert weights): out[c*R+r] = in[r*C+c] ----------
__global__ __launch_bounds__(256) void k_transpose(const float* __restrict__ in,
                                                   unsigned short* __restrict__ out,
                                                   int R, int C) {
    __shared__ float tile[32][33];
    const int c0 = blockIdx.x * 32, r0 = blockIdx.y * 32;
    const size_t base = (size_t)blockIdx.z * R * C;
    in += base; out += base;
    const int tx = threadIdx.x & 31, ty = threadIdx.x >> 5;
    #pragma unroll
    for (int i = 0; i < 32; i += 8)
        tile[ty + i][tx] = in[(size_t)(r0 + ty + i) * C + c0 + tx];
    __syncthreads();
    const int c = threadIdx.x >> 3, rq = (threadIdx.x & 7) * 4;
    ushort4 v;
    v.x = f2bf(tile[rq + 0][c]);
    v.y = f2bf(tile[rq + 1][c]);
    v.z = f2bf(tile[rq + 2][c]);
    v.w = f2bf(tile[rq + 3][c]);
    *(ushort4*)(out + (size_t)(c0 + c) * R + r0 + rq) = v;
}

// ---------- bf16 transpose for V: [32][T][HD] -> [32][HD][T] ----------
__global__ __launch_bounds__(256) void k_transpose_v(const unsigned short* __restrict__ in,
                                                     unsigned short* __restrict__ out) {
    const int bh = blockIdx.x;
    const int t0 = blockIdx.y * 128;
    const int tid = threadIdx.x;
    const int hd = tid & 63;
    const size_t ib = (size_t)bh * T_ * HD_;
    const size_t ob = (size_t)bh * HD_ * T_;
    for (int tb = tid >> 6; tb < 16; tb += 4) {
        const int t = t0 + tb * 8;
        short8_t v;
        #pragma unroll
        for (int k = 0; k < 8; ++k)
            v[k] = (short)in[ib + (size_t)(t + k) * HD_ + hd];
        *(short8_t*)(out + ob + (size_t)hd * T_ + t) = v;
    }
}

// ---------- fused: LayerNorm1 (bf16 out), x2 = x + bo, routing init ----------
__global__ __launch_bounds__(256) void k_ln_x2(const float* __restrict__ x,
                                               const float* __restrict__ g,
                                               const float* __restrict__ b,
                                               const float* __restrict__ bo,
                                               unsigned short* __restrict__ out,
                                               float* __restrict__ x2,
                                               int* __restrict__ counts, int* __restrict__ cursor,
                                               int* __restrict__ perm) {
    __shared__ float sm[16];
    const int row = blockIdx.x, tid = threadIdx.x;
    if (row == 0) {   // routing init (runs long before k_ln2_gate/k_scatter)
        if (tid < E_) { counts[tid] = 0; cursor[tid] = 0; }
        for (int i = tid; i < PADROWS; i += 256) perm[i] = -1;
    }
    const float4 v = *(const float4*)(x + (size_t)row * D_ + tid * 4);
    float s1 = v.x + v.y + v.z + v.w;
    float s2 = v.x * v.x + v.y * v.y + v.z * v.z + v.w * v.w;
    blockReduce2(s1, s2, sm);
    const float mean = s1 * (1.f / D_);
    const float inv  = rsqrtf(s2 * (1.f / D_) - mean * mean + 1e-5f);
    const float4 gg = *(const float4*)(g + tid * 4);
    const float4 bb = *(const float4*)(b + tid * 4);
    unsigned long long pk =
          (unsigned long long)f2bf((v.x - mean) * inv * gg.x + bb.x)
        | ((unsigned long long)f2bf((v.y - mean) * inv * gg.y + bb.y) << 16)
        | ((unsigned long long)f2bf((v.z - mean) * inv * gg.z + bb.z) << 32)
        | ((unsigned long long)f2bf((v.w - mean) * inv * gg.w + bb.w) << 48);
    *(unsigned long long*)(out + (size_t)row * D_ + tid * 4) = pk;
    const float4 bv = *(const float4*)(bo + tid * 4);
    float4 o; o.x = v.x + bv.x; o.y = v.y + bv.y; o.z = v.z + bv.z; o.w = v.w + bv.w;
    *(float4*)(x2 + (size_t)row * D_ + tid * 4) = o;
}

__global__ __launch_bounds__(256) void k_init_out(const float* __restrict__ x2u,
                                                  const float* __restrict__ eb2,
                                                  const int* __restrict__ assign,
                                                  float* __restrict__ out) {
    const int row = blockIdx.x, tid = threadIdx.x;
    const int e = assign[row];
    const size_t idx = (size_t)row * D_ + tid * 4;
    const float4 v = *(const float4*)(x2u + idx);
    const float4 b = *(const float4*)(eb2 + (size_t)e * D_ + tid * 4);
    float4 o; o.x = v.x + b.x; o.y = v.y + b.y; o.z = v.z + b.z; o.w = v.w + b.w;
    *(float4*)(out + idx) = o;
}

// ---------- shared 128x128xK bf16 GEMM core: 3-buffer depth-2, issue-early, setprio ----------
// T14: tile k+2 loads issue right after the barrier (before the ds_read/MFMA chain),
// giving them a full step of extra lead and an uncontended issue slot. Safe: the target
// buffer's readers all finished before the barrier. T5: setprio(1) around the MFMA cluster.
__device__ __forceinline__ void gemm_core(const unsigned short* ap0, const unsigned short* ap1,
                                          const unsigned short* bp0, const unsigned short* bp1,
                                          int K, unsigned short* Als, unsigned short* Bls,
                                          f32x4_t (&acc)[4][4]) {
    const int tid = threadIdx.x, w = tid >> 6, l = tid & 63;
    const int wm = (w >> 1) * 64, wn = (w & 1) * 64;
    const int fr = l & 15, fg = (l >> 4) * 8;
    const int fgs = fg ^ (((fr >> 1) & 3) << 3);   // T2 swizzled k-slot
    f32x4_t z4 = {0.f, 0.f, 0.f, 0.f};
    #pragma unroll
    for (int m = 0; m < 4; m++)
        #pragma unroll
        for (int n = 0; n < 4; n++) acc[m][n] = z4;
    glds16(ap0, Als + w * 512);
    glds16(ap1, Als + (w + 4) * 512);
    glds16(bp0, Bls + w * 512);
    glds16(bp1, Bls + (w + 4) * 512);
    ap0 += 32; ap1 += 32; bp0 += 32; bp1 += 32;
    glds16(ap0, Als + 4096 + w * 512);
    glds16(ap1, Als + 4096 + (w + 4) * 512);
    glds16(bp0, Bls + 4096 + w * 512);
    glds16(bp1, Bls + 4096 + (w + 4) * 512);
    ap0 += 32; ap1 += 32; bp0 += 32; bp1 += 32;
    unsigned c0 = 0, c1 = 4096, c2 = 8192;
    const int nk = K >> 5;
    for (int kt = 0; kt < nk; ++kt) {
        if (kt < nk - 1) asm volatile("s_waitcnt vmcnt(4)" ::: "memory");
        else             asm volatile("s_waitcnt vmcnt(0)" ::: "memory");
        __builtin_amdgcn_s_barrier();
        __builtin_amdgcn_sched_barrier(0);
        if (kt + 2 < nk) {                    // T14 issue-early: stage tile k+2 first
            glds16(ap0, Als + c2 + w * 512);
            glds16(ap1, Als + c2 + (w + 4) * 512);
            glds16(bp0, Bls + c2 + w * 512);
            glds16(bp1, Bls + c2 + (w + 4) * 512);
            ap0 += 32; ap1 += 32; bp0 += 32; bp1 += 32;
        }
        short8_t a[4], b[4];
        #pragma unroll
        for (int m = 0; m < 4; m++) a[m] = *(const short8_t*)(Als + c0 + (wm + m * 16 + fr) * 32 + fgs);
        #pragma unroll
        for (int n = 0; n < 4; n++) b[n] = *(const short8_t*)(Bls + c0 + (wn + n * 16 + fr) * 32 + fgs);
        __builtin_amdgcn_s_setprio(1);
        #pragma unroll
        for (int m = 0; m < 4; m++)
            #pragma unroll
            for (int n = 0; n < 4; n++)
                acc[m][n] = __builtin_amdgcn_mfma_f32_16x16x32_bf16(a[m], b[n], acc[m][n], 0, 0, 0);
        __builtin_amdgcn_s_setprio(0);
        const unsigned t = c0; c0 = c1; c1 = c2; c2 = t;
    }
}

// ---------- GEMM: h1 @ [Wq|Wk|Wv] + bias, scale q, scatter into [B,H,T,HD] ----------
__global__ __launch_bounds__(256) void k_gemm_qkv(
    const unsigned short* __restrict__ A, const unsigned short* __restrict__ BT,
    const float* __restrict__ bq, const float* __restrict__ bk, const float* __restrict__ bv,
    unsigned short* __restrict__ Qb, unsigned short* __restrict__ Kb, unsigned short* __restrict__ Vb) {
    __shared__ unsigned short Als[12288], Bls[12288];
    const int tid = threadIdx.x, w = tid >> 6, l = tid & 63;
    const int col0 = blockIdx.x * 128, row0 = blockIdx.y * 128;
    const int r0s = w * 16 + (l >> 2), r1s = 64 + w * 16 + (l >> 2);
    const int cs = ((l & 3) ^ ((l >> 3) & 3)) * 8;
    const unsigned short* ap0 = A + (size_t)(row0 + r0s) * D_ + cs;
    const unsigned short* ap1 = A + (size_t)(row0 + r1s) * D_ + cs;
    const unsigned short* bp0 = BT + (size_t)(col0 + r0s) * D_ + cs;
    const unsigned short* bp1 = BT + (size_t)(col0 + r1s) * D_ + cs;
    f32x4_t acc[4][4];
    gemm_core(ap0, ap1, bp0, bp1, D_, Als, Bls, acc);
    const int wm = (w >> 1) * 64, wn = (w & 1) * 64, fr = l & 15, fg4 = l >> 4;
    #pragma unroll
    for (int n = 0; n < 4; n++) {
        const int gcol = col0 + wn + n * 16 + fr;
        const int which = gcol >> 10, dc = gcol & 1023;
        const float bias = which == 0 ? bq[dc] : (which == 1 ? bk[dc] : bv[dc]);
        unsigned short* dst = which == 0 ? Qb : (which == 1 ? Kb : Vb);
        const int hh = dc >> 6, hd = dc & 63;
        #pragma unroll
        for (int m = 0; m < 4; m++)
            #pragma unroll
            for (int rr = 0; rr < 4; rr++) {
                const int grow = row0 + wm + m * 16 + fg4 * 4 + rr;
                float v = acc[m][n][rr] + bias;
                if (which == 0) v *= 0.1803368801111204f; // HD^-0.5 * log2(e)
                const int t = grow >> 1, bb = grow & 1;
                dst[((size_t)(bb * H_ + hh) * T_ + t) * HD_ + hd] = f2bf(v);
            }
    }
}

// ---------- causal flash attention v6b: issue-early staging + setprio ----------
__global__ __launch_bounds__(256) void k_attn(const unsigned short* __restrict__ Qb,
                                              const unsigned short* __restrict__ Kb,
                                              const unsigned short* __restrict__ Vt,
                                              unsigned short* __restrict__ aout) {
    __shared__ unsigned short Kl[3 * 4096];
    __shared__ unsigned short Vl[3 * 4096];
    const int id = blockIdx.x;
    const int qt = (id < 256) ? (15 - (id & 15)) : (id & 15);
    const int bh = (id >> 4) & 31;
    const int tid = threadIdx.x, w = tid >> 6, l = tid & 63;
    const int q5 = l & 31, hi = l >> 5, l7 = l & 7;
    const int row0 = w * 8 + (l >> 3);
    const int swz = ((l & 7) ^ (l >> 3)) * 8;
    const size_t base = (size_t)bh * T_ * HD_;
    const unsigned short* Qp = Qb + base;
    const unsigned short* kps = Kb + base + (size_t)row0 * HD_ + swz;
    const unsigned short* vps = Vt + base + (size_t)row0 * T_ + swz;
    const int qw0 = qt * 128 + w * 32;
    const int q = qw0 + q5;

    short8_t aq[4];
    #pragma unroll
    for (int khd = 0; khd < 4; ++khd)
        aq[khd] = *(const short8_t*)(Qp + (size_t)q * HD_ + khd * 16 + hi * 8);

    f32x16_t accO0, accO1;
    #pragma unroll
    for (int i = 0; i < 16; ++i) { accO0[i] = 0.f; accO1[i] = 0.f; }
    float mrun = -1e30f, lrun = 0.f;

    const int niter = (qt + 1) * 2;

#define STAGE_KV(t, b) { \
    const size_t ko = (size_t)(t) * 64 * HD_; const int vo = (t) * 64; \
    glds16(kps + ko,            Kl + (b) + w * 512); \
    glds16(kps + ko + 32 * HD_, Kl + (b) + 2048 + w * 512); \
    glds16(vps + vo,            Vl + (b) + w * 512); \
    glds16(vps + vo + 32 * T_,  Vl + (b) + 2048 + w * 512); }

    STAGE_KV(0, 0);
    STAGE_KV(1, 4096);
    unsigned c0 = 0, c1 = 4096, c2 = 8192;

    for (int it = 0; it < niter; ++it) {
        if (it < niter - 1) asm volatile("s_waitcnt vmcnt(4)" ::: "memory");
        else                asm volatile("s_waitcnt vmcnt(0)" ::: "memory");
        __builtin_amdgcn_s_barrier();
        __builtin_amdgcn_sched_barrier(0);
        if (it + 2 < niter) STAGE_KV(it + 2, c2);   // T14 issue-early
        const int s0 = it * 64;
        if (s0 <= qw0 + 31) {
            const unsigned short* KT = Kl + c0;
            const unsigned short* VT = Vl + c0;

            f32x16_t st0, st1;
            #pragma unroll
            for (int i = 0; i < 16; ++i) { st0[i] = 0.f; st1[i] = 0.f; }
            __builtin_amdgcn_s_setprio(1);
            #pragma unroll
            for (int khd = 0; khd < 4; ++khd) {
                const int cb = (khd * 16 + hi * 8) ^ (l7 * 8);
                const short8_t k0 = *(const short8_t*)(KT + q5 * 64 + cb);
                const short8_t k1 = *(const short8_t*)(KT + (32 + q5) * 64 + cb);
                st0 = __builtin_amdgcn_mfma_f32_32x32x16_bf16(k0, aq[khd], st0, 0, 0, 0);
                st1 = __builtin_amdgcn_mfma_f32_32x32x16_bf16(k1, aq[khd], st1, 0, 0, 0);
            }
            __builtin_amdgcn_s_setprio(0);

            const bool domask = (s0 + 63 > qw0);
            float pmax = -3e38f;
            #pragma unroll
            for (int r = 0; r < 16; ++r) {
                float v0 = st0[r], v1 = st1[r];
                if (domask) {
                    const int kv0 = s0 + (r & 3) + 8 * (r >> 2) + 4 * hi;
                    if (kv0 > q)      v0 = -1e30f;
                    if (kv0 + 32 > q) v1 = -1e30f;
                }
                st0[r] = v0; st1[r] = v1;
                pmax = fmaxf(pmax, fmaxf(v0, v1));
            }
            pmax = fmaxf(pmax, __shfl_xor(pmax, 32));
            const float mnew = fmaxf(mrun, pmax);
            const float scl = exp2f(mrun - mnew);
            float pt0[16], pt1[16];
            float rs = 0.f;
            #pragma unroll
            for (int r = 0; r < 16; ++r) {
                pt0[r] = exp2f(st0[r] - mnew);
                pt1[r] = exp2f(st1[r] - mnew);
                rs += pt0[r] + pt1[r];
            }
            rs += __shfl_xor(rs, 32);
            lrun = lrun * scl + rs;
            mrun = mnew;
            #pragma unroll
            for (int i = 0; i < 16; ++i) { accO0[i] *= scl; accO1[i] *= scl; }

            unsigned Wp[2][4][2];
            #pragma unroll
            for (int b = 0; b < 4; ++b) {
                Wp[0][b][0] = cvtpk(pt0[4 * b + 0], pt0[4 * b + 1]);
                Wp[0][b][1] = cvtpk(pt0[4 * b + 2], pt0[4 * b + 3]);
                Wp[1][b][0] = cvtpk(pt1[4 * b + 0], pt1[4 * b + 1]);
                Wp[1][b][1] = cvtpk(pt1[4 * b + 2], pt1[4 * b + 3]);
            }

            __builtin_amdgcn_s_setprio(1);
            #pragma unroll
            for (int ks = 0; ks < 4; ++ks) {
                const int t = ks >> 1, b0 = (ks & 1) * 2;
                const unsigned ownA0 = Wp[t][b0][0],     ownA1 = Wp[t][b0][1];
                const unsigned ownB0 = Wp[t][b0 + 1][0], ownB1 = Wp[t][b0 + 1][1];
                const unsigned send0 = hi ? ownA0 : ownB0;
                const unsigned send1 = hi ? ownA1 : ownB1;
                const unsigned recv0 = __shfl_xor(send0, 32);
                const unsigned recv1 = __shfl_xor(send1, 32);
                u32x4_t wds;
                wds[0] = hi ? recv0 : ownA0;
                wds[1] = hi ? recv1 : ownA1;
                wds[2] = hi ? ownB0 : recv0;
                wds[3] = hi ? ownB1 : recv1;
                const short8_t pfrag = __builtin_bit_cast(short8_t, wds);
                const int cb = (ks * 16 + hi * 8) ^ (l7 * 8);
                const short8_t v0 = *(const short8_t*)(VT + q5 * 64 + cb);
                const short8_t v1 = *(const short8_t*)(VT + (32 + q5) * 64 + cb);
                accO0 = __builtin_amdgcn_mfma_f32_32x32x16_bf16(v0, pfrag, accO0, 0, 0, 0);
                accO1 = __builtin_amdgcn_mfma_f32_32x32x16_bf16(v1, pfrag, accO1, 0, 0, 0);
            }
            __builtin_amdgcn_s_setprio(0);
        }
        const unsigned tb = c0; c0 = c1; c1 = c2; c2 = tb;
    }
#undef STAGE_KV

    const float linv = 1.f / lrun;
    const int bidx = bh >> 4, hidx = bh & 15;
    unsigned short* orow = aout + (size_t)(q * B_ + bidx) * D_ + hidx * 64;
    #pragma unroll
    for (int g = 0; g < 4; ++g) {
        const int hd0 = 8 * g + 4 * hi;
        unsigned long long pk0 =
              (unsigned long long)f2bf(accO0[4 * g + 0] * linv)
            | ((unsigned long long)f2bf(accO0[4 * g + 1] * linv) << 16)
            | ((unsigned long long)f2bf(accO0[4 * g + 2] * linv) << 32)
            | ((unsigned long long)f2bf(accO0[4 * g + 3] * linv) << 48);
        *(unsigned long long*)(orow + hd0) = pk0;
        unsigned long long pk1 =
              (unsigned long long)f2bf(accO1[4 * g + 0] * linv)
            | ((unsigned long long)f2bf(accO1[4 * g + 1] * linv) << 16)
            | ((unsigned long long)f2bf(accO1[4 * g + 2] * linv) << 32)
            | ((unsigned long long)f2bf(accO1[4 * g + 3] * linv) << 48);
        *(unsigned long long*)(orow + 32 + hd0) = pk1;
    }
}

// ---------- O-projection, split-K=2: x2 += aout @ Wo (atomic; x2 pre-init with x+bo) ----------
__global__ __launch_bounds__(256) void k_gemm_o(
    const unsigned short* __restrict__ A, const unsigned short* __restrict__ BT,
    float* __restrict__ x2) {
    __shared__ unsigned short Als[12288], Bls[12288];
    const int tid = threadIdx.x, w = tid >> 6, l = tid & 63;
    const int row0 = blockIdx.x * 128, col0 = blockIdx.y * 128;
    const int kc = blockIdx.z * 512;
    const int r0s = w * 16 + (l >> 2), r1s = 64 + w * 16 + (l >> 2);
    const int cs = ((l & 3) ^ ((l >> 3) & 3)) * 8;
    const unsigned short* ap0 = A + (size_t)(row0 + r0s) * D_ + kc + cs;
    const unsigned short* ap1 = A + (size_t)(row0 + r1s) * D_ + kc + cs;
    const unsigned short* bp0 = BT + (size_t)(col0 + r0s) * D_ + kc + cs;
    const unsigned short* bp1 = BT + (size_t)(col0 + r1s) * D_ + kc + cs;
    f32x4_t acc[4][4];
    gemm_core(ap0, ap1, bp0, bp1, 512, Als, Bls, acc);
    const int wm = (w >> 1) * 64, wn = (w & 1) * 64, fr = l & 15, fg4 = l >> 4;
    #pragma unroll
    for (int n = 0; n < 4; n++) {
        const int gcol = col0 + wn + n * 16 + fr;
        #pragma unroll
        for (int m = 0; m < 4; m++)
            #pragma unroll
            for (int rr = 0; rr < 4; rr++) {
                const int grow = row0 + wm + m * 16 + fg4 * 4 + rr;
                atomicAdd(&x2[(size_t)grow * D_ + gcol], acc[m][n][rr]);
            }
    }
}

// ---------- LN2 + gating + expert-LN; x2 <- x2 + u (in place) ----------
__global__ __launch_bounds__(256) void k_ln2_gate(
    float* __restrict__ x2, const float* __restrict__ g2, const float* __restrict__ b2,
    const float* __restrict__ cent, const float* __restrict__ eg, const float* __restrict__ eb,
    unsigned short* __restrict__ z, int* __restrict__ assign, int* __restrict__ counts) {
    __shared__ float sm[48];
    const int row = blockIdx.x, tid = threadIdx.x;
    const int w = tid >> 6, l = tid & 63;
    float* xr = x2 + (size_t)row * D_;
    const float4 v = *(const float4*)(xr + tid * 4);
    float s1 = v.x + v.y + v.z + v.w;
    float s2 = v.x * v.x + v.y * v.y + v.z * v.z + v.w * v.w;
    blockReduce2(s1, s2, sm);
    const float mean = s1 * (1.f / D_);
    const float inv  = rsqrtf(s2 * (1.f / D_) - mean * mean + 1e-5f);
    const float4 gg = *(const float4*)(g2 + tid * 4), bb = *(const float4*)(b2 + tid * 4);
    float4 u;
    u.x = (v.x - mean) * inv * gg.x + bb.x;
    u.y = (v.y - mean) * inv * gg.y + bb.y;
    u.z = (v.z - mean) * inv * gg.z + bb.z;
    u.w = (v.w - mean) * inv * gg.w + bb.w;
    float p[E_];
    #pragma unroll
    for (int e = 0; e < E_; e++) {
        const float4 c = *(const float4*)(cent + (size_t)e * D_ + tid * 4);
        p[e] = u.x * c.x + u.y * c.y + u.z * c.z + u.w * c.w;
    }
    #pragma unroll
    for (int m = 32; m; m >>= 1)
        #pragma unroll
        for (int e = 0; e < E_; e++) p[e] += __shfl_xor(p[e], m);
    __syncthreads();
    if (l == 0) {
        #pragma unroll
        for (int e = 0; e < E_; e++) sm[16 + e * 4 + w] = p[e];
    }
    __syncthreads();
    int best = 0; float bl = -1e30f;
    #pragma unroll
    for (int e = 0; e < E_; e++) {
        const float le = sm[16 + e * 4] + sm[16 + e * 4 + 1] + sm[16 + e * 4 + 2] + sm[16 + e * 4 + 3];
        if (le > bl) { bl = le; best = e; }
    }
    float t1 = u.x + u.y + u.z + u.w;
    float t2 = u.x * u.x + u.y * u.y + u.z * u.z + u.w * u.w;
    blockReduce2(t1, t2, sm);
    const float m2   = t1 * (1.f / D_);
    const float inv2 = rsqrtf(t2 * (1.f / D_) - m2 * m2 + 1e-5f);
    const float4 egv = *(const float4*)(eg + (size_t)best * D_ + tid * 4);
    const float4 ebv = *(const float4*)(eb + (size_t)best * D_ + tid * 4);
    unsigned long long pk =
          (unsigned long long)f2bf((u.x - m2) * inv2 * egv.x + ebv.x)
        | ((unsigned long long)f2bf((u.y - m2) * inv2 * egv.y + ebv.y) << 16)
        | ((unsigned long long)f2bf((u.z - m2) * inv2 * egv.z + ebv.z) << 32)
        | ((unsigned long long)f2bf((u.w - m2) * inv2 * egv.w + ebv.w) << 48);
    *(unsigned long long*)(z + (size_t)row * D_ + tid * 4) = pk;
    float4 xu; xu.x = v.x + u.x; xu.y = v.y + u.y; xu.z = v.z + u.z; xu.w = v.w + u.w;
    *(float4*)(xr + tid * 4) = xu;
    if (tid == 0) { assign[row] = best; atomicAdd(&counts[best], 1); }
}

// ---------- routing bookkeeping ----------
__global__ void k_offsets(const int* counts, int* pad_off) {
    if (threadIdx.x == 0) {
        int o = 0; pad_off[0] = 0;
        for (int e = 0; e < E_; e++) { o += ((counts[e] + 127) >> 7) << 7; pad_off[e + 1] = o; }
    }
}

__global__ void k_scatter(const int* assign, const int* pad_off, int* cursor, int* perm) {
    const int r = blockIdx.x * 256 + threadIdx.x;
    if (r >= N_) return;
    const int e = assign[r];
    const int pos = pad_off[e] + atomicAdd(&cursor[e], 1);
    perm[pos] = r;
}

// ---------- expert FFN GEMM 1: Y1 = relu(z[perm] @ W1_e + b1_e), bf16 ----------
__global__ __launch_bounds__(256) void k_gemm_e1(
    const unsigned short* __restrict__ z, const unsigned short* __restrict__ W1T,
    const float* __restrict__ eb1, const int* __restrict__ pad_off,
    const int* __restrict__ perm, unsigned short* __restrict__ Y1) {
    __shared__ unsigned short Als[12288], Bls[12288];
    const int tid = threadIdx.x, w = tid >> 6, l = tid & 63;
    const int col0 = blockIdx.x * 128, row0 = blockIdx.y * 128;
    if (row0 >= pad_off[E_]) return;
    int e = 0;
    while (row0 >= pad_off[e + 1]) e++;
    const int r0s = w * 16 + (l >> 2), r1s = 64 + w * 16 + (l >> 2);
    const int cs = ((l & 3) ^ ((l >> 3) & 3)) * 8;
    int pr0 = perm[row0 + r0s]; if (pr0 < 0) pr0 = 0;
    int pr1 = perm[row0 + r1s]; if (pr1 < 0) pr1 = 0;
    const unsigned short* ap0 = z + (size_t)pr0 * D_ + cs;
    const unsigned short* ap1 = z + (size_t)pr1 * D_ + cs;
    const unsigned short* BTe = W1T + (size_t)e * F_ * D_;
    const unsigned short* bp0 = BTe + (size_t)(col0 + r0s) * D_ + cs;
    const unsigned short* bp1 = BTe + (size_t)(col0 + r1s) * D_ + cs;
    f32x4_t acc[4][4];
    gemm_core(ap0, ap1, bp0, bp1, D_, Als, Bls, acc);
    const float* b1e = eb1 + (size_t)e * F_;
    const int wm = (w >> 1) * 64, wn = (w & 1) * 64, fr = l & 15, fg4 = l >> 4;
    #pragma unroll
    for (int n = 0; n < 4; n++) {
        const int gcol = col0 + wn + n * 16 + fr;
        const float bias = b1e[gcol];
        #pragma unroll
        for (int m = 0; m < 4; m++)
            #pragma unroll
            for (int rr = 0; rr < 4; rr++) {
                const int grow = row0 + wm + m * 16 + fg4 * 4 + rr;
                Y1[(size_t)grow * F_ + gcol] = f2bf(fmaxf(acc[m][n][rr] + bias, 0.f));
            }
    }
}

// ---------- expert FFN GEMM 2, split-K=2: out += Y1 @ W2_e (atomic; out pre-init) ----------
__global__ __launch_bounds__(256) void k_gemm_e2(
    const unsigned short* __restrict__ Y1, const unsigned short* __restrict__ W2T,
    const int* __restrict__ pad_off, const int* __restrict__ perm,
    float* __restrict__ out) {
    __shared__ unsigned short Als[12288], Bls[12288];
    const int tid = threadIdx.x, w = tid >> 6, l = tid & 63;
    const int row0 = blockIdx.x * 128, col0 = blockIdx.y * 128;
    const int kc = blockIdx.z * 2048;
    if (row0 >= pad_off[E_]) return;
    int e = 0;
    while (row0 >= pad_off[e + 1]) e++;
    const int r0s = w * 16 + (l >> 2), r1s = 64 + w * 16 + (l >> 2);
    const int cs = ((l & 3) ^ ((l >> 3) & 3)) * 8;
    const unsigned short* ap0 = Y1 + (size_t)(row0 + r0s) * F_ + kc + cs;
    const unsigned short* ap1 = Y1 + (size_t)(row0 + r1s) * F_ + kc + cs;
    const unsigned short* BTe = W2T + (size_t)e * D_ * F_;
    const unsigned short* bp0 = BTe + (size_t)(col0 + r0s) * F_ + kc + cs;
    const unsigned short* bp1 = BTe + (size_t)(col0 + r1s) * F_ + kc + cs;
    f32x4_t acc[4][4];
    gemm_core(ap0, ap1, bp0, bp1, 2048, Als, Bls, acc);
    const int wm = (w >> 1) * 64, wn = (w & 1) * 64, fr = l & 15, fg4 = l >> 4;
    #pragma unroll
    for (int n = 0; n < 4; n++) {
        const int gcol = col0 + wn + n * 16 + fr;
        #pragma unroll
        for (int m = 0; m < 4; m++)
            #pragma unroll
            for (int rr = 0; rr < 4; rr++) {
                const int grow = row0 + wm + m * 16 + fg4 * 4 + rr;
                const int rdst = perm[grow];
                if (rdst >= 0)
                    atomicAdd(&out[(size_t)rdst * D_ + gcol], acc[m][n][rr]);
            }
    }
}

extern "C" void kernel_launch(void* const* d_in, const int* in_sizes, int n_in,
                              void* d_out, int out_size, void* d_ws, size_t ws_size,
                              hipStream_t stream) {
    const float* x    = (const float*)d_in[0];
    const float* Wq   = (const float*)d_in[1];
    const float* bq   = (const float*)d_in[2];
    const float* Wk   = (const float*)d_in[3];
    const float* bk   = (const float*)d_in[4];
    const float* Wv   = (const float*)d_in[5];
    const float* bv   = (const float*)d_in[6];
    const float* Wo   = (const float*)d_in[7];
    const float* bo   = (const float*)d_in[8];
    const float* ln1g = (const float*)d_in[9];
    const float* ln1b = (const float*)d_in[10];
    const float* ln2g = (const float*)d_in[11];
    const float* ln2b = (const float*)d_in[12];
    const float* cent = (const float*)d_in[13];
    const float* egw  = (const float*)d_in[14];
    const float* ebw  = (const float*)d_in[15];
    const float* eW1  = (const float*)d_in[16];
    const float* eb1  = (const float*)d_in[17];
    const float* eW2  = (const float*)d_in[18];
    const float* eb2  = (const float*)d_in[19];
    float* out = (float*)d_out;

    char* W = (char*)d_ws;
    unsigned short* WqkvT = (unsigned short*)(W);                 //  6291456 B
    unsigned short* WoT   = (unsigned short*)(W + 6291456);       //  2097152 B
    unsigned short* Qb    = (unsigned short*)(W + 8388608);       //  8388608 B
    unsigned short* Kb    = (unsigned short*)(W + 16777216);      //  8388608 B
    unsigned short* Vb    = (unsigned short*)(W + 25165824);      //  8388608 B
    unsigned short* aout  = (unsigned short*)(W + 33554432);      //  8388608 B -> ends 41943040
    unsigned short* Y1    = (unsigned short*)(W);                 // 41943040 B (alias, all above dead)
    unsigned short* W1T   = (unsigned short*)(W + 41943040);      // 67108864 B
    unsigned short* W2T   = (unsigned short*)(W + 109051904);     // 67108864 B
    unsigned short* h1z   = (unsigned short*)(W + 176160768);     //  8388608 B (h1, later z)
    float*          x2    = (float*)(W + 184549376);              // 16777216 B -> ends 201326592
    unsigned short* Vt    = (unsigned short*)(W + 201326592);     //  8388608 B -> ends 209715200
    int*            assign= (int*)(W + 209715200);
    int*            perm  = (int*)(W + 209731584);
    int*            counts= (int*)(W + 209752064);
    int*            cursor= (int*)(W + 209752192);
    int*            pad_off=(int*)(W + 209752320);

    // weight transposes (fp32 -> bf16, B^T layout)
    k_transpose4<<<dim3(32, 32, 4), 256, 0, stream>>>(Wq, Wk, Wv, Wo, WqkvT, WoT);
    k_transpose<<<dim3(128, 32, 8), 256, 0, stream>>>(eW1, W1T, 1024, 4096);
    k_transpose<<<dim3(32, 128, 8), 256, 0, stream>>>(eW2, W2T, 4096, 1024);

    k_ln_x2<<<N_, 256, 0, stream>>>(x, ln1g, ln1b, bo, h1z, x2, counts, cursor, perm);
    k_gemm_qkv<<<dim3(24, 32), 256, 0, stream>>>(h1z, WqkvT, bq, bk, bv, Qb, Kb, Vb);
    k_transpose_v<<<dim3(32, 16), 256, 0, stream>>>(Vb, Vt);
    k_attn<<<dim3(512), 256, 0, stream>>>(Qb, Kb, Vt, aout);
    k_gemm_o<<<dim3(32, 8, 2), 256, 0, stream>>>(aout, WoT, x2);
    k_ln2_gate<<<N_, 256, 0, stream>>>(x2, ln2g, ln2b, cent, egw, ebw, h1z, assign, counts);
    k_offsets<<<1, 64, 0, stream>>>(counts, pad_off);
    k_scatter<<<16, 256, 0, stream>>>(assign, pad_off, cursor, perm);
    k_init_out<<<N_, 256, 0, stream>>>(x2, eb2, assign, out);
    k_gemm_e1<<<dim3(32, 40), 256, 0, stream>>>(h1z, W1T, eb1, pad_off, perm, Y1);
    k_gemm_e2<<<dim3(40, 8, 2), 256, 0, stream>>>(Y1, W2T, pad_off, perm, out);
}

// Round 13
// 463.940 us; speedup vs baseline: 1.0577x; 1.0375x over previous
//
#include <hip/hip_runtime.h>
#include <hip/hip_bf16.h>
#include <math.h>

// Problem dims
#define T_ 2048
#define B_ 2
#define D_ 1024
#define H_ 16
#define F_ 4096
#define E_ 8
#define N_ 4096      // T_*B_ tokens, row r = t*B_ + b (memory order of x[T,B,D])
#define HD_ 64
#define PADROWS 5120 // N_ + E_*128 worst-case padded rows

typedef __attribute__((ext_vector_type(8))) short short8_t;
typedef __attribute__((ext_vector_type(4))) float f32x4_t;
typedef __attribute__((ext_vector_type(16))) float f32x16_t;
typedef __attribute__((ext_vector_type(4))) unsigned u32x4_t;

__device__ __forceinline__ unsigned short f2bf(float f) {
    union { float f; unsigned u; } a; a.f = f;
    unsigned r = a.u + 0x7FFFu + ((a.u >> 16) & 1u);   // RNE
    return (unsigned short)(r >> 16);
}

__device__ __forceinline__ unsigned cvtpk(float lo, float hi) {
    unsigned r;
    asm("v_cvt_pk_bf16_f32 %0, %1, %2" : "=v"(r) : "v"(lo), "v"(hi));
    return r;
}

__device__ __forceinline__ void glds16(const unsigned short* g, unsigned short* l) {
    __builtin_amdgcn_global_load_lds(
        (const __attribute__((address_space(1))) void*)g,
        (__attribute__((address_space(3))) void*)l, 16, 0, 0);
}

__device__ __forceinline__ void blockReduce2(float& a, float& b, float* sm) {
    #pragma unroll
    for (int m = 32; m; m >>= 1) { a += __shfl_xor(a, m); b += __shfl_xor(b, m); }
    const int w = threadIdx.x >> 6, l = threadIdx.x & 63;
    __syncthreads();
    if (l == 0) { sm[w] = a; sm[8 + w] = b; }
    __syncthreads();
    a = sm[0] + sm[1] + sm[2] + sm[3];
    b = sm[8] + sm[9] + sm[10] + sm[11];
}

// ---------- fused transpose of the four 1024x1024 fp32 weights -> bf16 B^T ----------
__global__ __launch_bounds__(256) void k_transpose4(
    const float* __restrict__ Wq, const float* __restrict__ Wk,
    const float* __restrict__ Wv, const float* __restrict__ Wo,
    unsigned short* __restrict__ WqkvT, unsigned short* __restrict__ WoT) {
    __shared__ float tile[32][33];
    const int zi = blockIdx.z;
    const float* in = zi == 0 ? Wq : (zi == 1 ? Wk : (zi == 2 ? Wv : Wo));
    unsigned short* out = zi == 3 ? WoT : (WqkvT + (size_t)zi * 1024 * 1024);
    const int c0 = blockIdx.x * 32, r0 = blockIdx.y * 32;
    const int tx = threadIdx.x & 31, ty = threadIdx.x >> 5;
    #pragma unroll
    for (int i = 0; i < 32; i += 8)
        tile[ty + i][tx] = in[(size_t)(r0 + ty + i) * 1024 + c0 + tx];
    __syncthreads();
    const int c = threadIdx.x >> 3, rq = (threadIdx.x & 7) * 4;
    ushort4 v;
    v.x = f2bf(tile[rq + 0][c]);
    v.y = f2bf(tile[rq + 1][c]);
    v.z = f2bf(tile[rq + 2][c]);
    v.w = f2bf(tile[rq + 3][c]);
    *(ushort4*)(out + (size_t)(c0 + c) * 1024 + r0 + rq) = v;
}

// ---------- transpose + fp32->bf16 convert (expert weights): out[c*R+r] = in[r*C+c] ----------
__global__ __launch_bounds__(256) void k_transpose(const float* __restrict__ in,
                                                   unsigned short* __restrict__ out,
                                                   int R, int C) {
    __shared__ float tile[32][33];
    const int c0 = blockIdx.x * 32, r0 = blockIdx.y * 32;
    const size_t base = (size_t)blockIdx.z * R * C;
    in += base; out += base;
    const int tx = threadIdx.x & 31, ty = threadIdx.x >> 5;
    #pragma unroll
    for (int i = 0; i < 32; i += 8)
        tile[ty + i][tx] = in[(size_t)(r0 + ty + i) * C + c0 + tx];
    __syncthreads();
    const int c = threadIdx.x >> 3, rq = (threadIdx.x & 7) * 4;
    ushort4 v;
    v.x = f2bf(tile[rq + 0][c]);
    v.y = f2bf(tile[rq + 1][c]);
    v.z = f2bf(tile[rq + 2][c]);
    v.w = f2bf(tile[rq + 3][c]);
    *(ushort4*)(out + (size_t)(c0 + c) * R + r0 + rq) = v;
}

// ---------- bf16 transpose for V: [32][T][HD] -> [32][HD][T] ----------
__global__ __launch_bounds__(256) void k_transpose_v(const unsigned short* __restrict__ in,
                                                     unsigned short* __restrict__ out) {
    const int bh = blockIdx.x;
    const int t0 = blockIdx.y * 128;
    const int tid = threadIdx.x;
    const int hd = tid & 63;
    const size_t ib = (size_t)bh * T_ * HD_;
    const size_t ob = (size_t)bh * HD_ * T_;
    for (int tb = tid >> 6; tb < 16; tb += 4) {
        const int t = t0 + tb * 8;
        short8_t v;
        #pragma unroll
        for (int k = 0; k < 8; ++k)
            v[k] = (short)in[ib + (size_t)(t + k) * HD_ + hd];
        *(short8_t*)(out + ob + (size_t)hd * T_ + t) = v;
    }
}

// ---------- fused: LayerNorm1 (bf16 out), x2 = x + bo, routing init ----------
__global__ __launch_bounds__(256) void k_ln_x2(const float* __restrict__ x,
                                               const float* __restrict__ g,
                                               const float* __restrict__ b,
                                               const float* __restrict__ bo,
                                               unsigned short* __restrict__ out,
                                               float* __restrict__ x2,
                                               int* __restrict__ counts, int* __restrict__ cursor,
                                               int* __restrict__ perm) {
    __shared__ float sm[16];
    const int row = blockIdx.x, tid = threadIdx.x;
    if (row == 0) {
        if (tid < E_) { counts[tid] = 0; cursor[tid] = 0; }
        for (int i = tid; i < PADROWS; i += 256) perm[i] = -1;
    }
    const float4 v = *(const float4*)(x + (size_t)row * D_ + tid * 4);
    float s1 = v.x + v.y + v.z + v.w;
    float s2 = v.x * v.x + v.y * v.y + v.z * v.z + v.w * v.w;
    blockReduce2(s1, s2, sm);
    const float mean = s1 * (1.f / D_);
    const float inv  = rsqrtf(s2 * (1.f / D_) - mean * mean + 1e-5f);
    const float4 gg = *(const float4*)(g + tid * 4);
    const float4 bb = *(const float4*)(b + tid * 4);
    unsigned long long pk =
          (unsigned long long)f2bf((v.x - mean) * inv * gg.x + bb.x)
        | ((unsigned long long)f2bf((v.y - mean) * inv * gg.y + bb.y) << 16)
        | ((unsigned long long)f2bf((v.z - mean) * inv * gg.z + bb.z) << 32)
        | ((unsigned long long)f2bf((v.w - mean) * inv * gg.w + bb.w) << 48);
    *(unsigned long long*)(out + (size_t)row * D_ + tid * 4) = pk;
    const float4 bv = *(const float4*)(bo + tid * 4);
    float4 o; o.x = v.x + bv.x; o.y = v.y + bv.y; o.z = v.z + bv.z; o.w = v.w + bv.w;
    *(float4*)(x2 + (size_t)row * D_ + tid * 4) = o;
}

__global__ __launch_bounds__(256) void k_init_out(const float* __restrict__ x2u,
                                                  const float* __restrict__ eb2,
                                                  const int* __restrict__ assign,
                                                  float* __restrict__ out) {
    const int row = blockIdx.x, tid = threadIdx.x;
    const int e = assign[row];
    const size_t idx = (size_t)row * D_ + tid * 4;
    const float4 v = *(const float4*)(x2u + idx);
    const float4 b = *(const float4*)(eb2 + (size_t)e * D_ + tid * 4);
    float4 o; o.x = v.x + b.x; o.y = v.y + b.y; o.z = v.z + b.z; o.w = v.w + b.w;
    *(float4*)(out + idx) = o;
}

// ---------- shared 128x128xK bf16 GEMM core: 3-buffer depth-2, issue-early, setprio ----------
__device__ __forceinline__ void gemm_core(const unsigned short* ap0, const unsigned short* ap1,
                                          const unsigned short* bp0, const unsigned short* bp1,
                                          int K, unsigned short* Als, unsigned short* Bls,
                                          f32x4_t (&acc)[4][4]) {
    const int tid = threadIdx.x, w = tid >> 6, l = tid & 63;
    const int wm = (w >> 1) * 64, wn = (w & 1) * 64;
    const int fr = l & 15, fg = (l >> 4) * 8;
    const int fgs = fg ^ (((fr >> 1) & 3) << 3);   // T2 swizzled k-slot
    f32x4_t z4 = {0.f, 0.f, 0.f, 0.f};
    #pragma unroll
    for (int m = 0; m < 4; m++)
        #pragma unroll
        for (int n = 0; n < 4; n++) acc[m][n] = z4;
    glds16(ap0, Als + w * 512);
    glds16(ap1, Als + (w + 4) * 512);
    glds16(bp0, Bls + w * 512);
    glds16(bp1, Bls + (w + 4) * 512);
    ap0 += 32; ap1 += 32; bp0 += 32; bp1 += 32;
    glds16(ap0, Als + 4096 + w * 512);
    glds16(ap1, Als + 4096 + (w + 4) * 512);
    glds16(bp0, Bls + 4096 + w * 512);
    glds16(bp1, Bls + 4096 + (w + 4) * 512);
    ap0 += 32; ap1 += 32; bp0 += 32; bp1 += 32;
    unsigned c0 = 0, c1 = 4096, c2 = 8192;
    const int nk = K >> 5;
    for (int kt = 0; kt < nk; ++kt) {
        if (kt < nk - 1) asm volatile("s_waitcnt vmcnt(4)" ::: "memory");
        else             asm volatile("s_waitcnt vmcnt(0)" ::: "memory");
        __builtin_amdgcn_s_barrier();
        __builtin_amdgcn_sched_barrier(0);
        if (kt + 2 < nk) {                    // T14 issue-early: stage tile k+2 first
            glds16(ap0, Als + c2 + w * 512);
            glds16(ap1, Als + c2 + (w + 4) * 512);
            glds16(bp0, Bls + c2 + w * 512);
            glds16(bp1, Bls + c2 + (w + 4) * 512);
            ap0 += 32; ap1 += 32; bp0 += 32; bp1 += 32;
        }
        short8_t a[4], b[4];
        #pragma unroll
        for (int m = 0; m < 4; m++) a[m] = *(const short8_t*)(Als + c0 + (wm + m * 16 + fr) * 32 + fgs);
        #pragma unroll
        for (int n = 0; n < 4; n++) b[n] = *(const short8_t*)(Bls + c0 + (wn + n * 16 + fr) * 32 + fgs);
        __builtin_amdgcn_s_setprio(1);
        #pragma unroll
        for (int m = 0; m < 4; m++)
            #pragma unroll
            for (int n = 0; n < 4; n++)
                acc[m][n] = __builtin_amdgcn_mfma_f32_16x16x32_bf16(a[m], b[n], acc[m][n], 0, 0, 0);
        __builtin_amdgcn_s_setprio(0);
        const unsigned t = c0; c0 = c1; c1 = c2; c2 = t;
    }
}

// ---------- GEMM: h1 @ [Wq|Wk|Wv] + bias, scale q, scatter into [B,H,T,HD] ----------
__global__ __launch_bounds__(256) void k_gemm_qkv(
    const unsigned short* __restrict__ A, const unsigned short* __restrict__ BT,
    const float* __restrict__ bq, const float* __restrict__ bk, const float* __restrict__ bv,
    unsigned short* __restrict__ Qb, unsigned short* __restrict__ Kb, unsigned short* __restrict__ Vb) {
    __shared__ unsigned short Als[12288], Bls[12288];
    const int tid = threadIdx.x, w = tid >> 6, l = tid & 63;
    const int col0 = blockIdx.x * 128, row0 = blockIdx.y * 128;
    const int r0s = w * 16 + (l >> 2), r1s = 64 + w * 16 + (l >> 2);
    const int cs = ((l & 3) ^ ((l >> 3) & 3)) * 8;
    const unsigned short* ap0 = A + (size_t)(row0 + r0s) * D_ + cs;
    const unsigned short* ap1 = A + (size_t)(row0 + r1s) * D_ + cs;
    const unsigned short* bp0 = BT + (size_t)(col0 + r0s) * D_ + cs;
    const unsigned short* bp1 = BT + (size_t)(col0 + r1s) * D_ + cs;
    f32x4_t acc[4][4];
    gemm_core(ap0, ap1, bp0, bp1, D_, Als, Bls, acc);
    const int wm = (w >> 1) * 64, wn = (w & 1) * 64, fr = l & 15, fg4 = l >> 4;
    #pragma unroll
    for (int n = 0; n < 4; n++) {
        const int gcol = col0 + wn + n * 16 + fr;
        const int which = gcol >> 10, dc = gcol & 1023;
        const float bias = which == 0 ? bq[dc] : (which == 1 ? bk[dc] : bv[dc]);
        unsigned short* dst = which == 0 ? Qb : (which == 1 ? Kb : Vb);
        const int hh = dc >> 6, hd = dc & 63;
        #pragma unroll
        for (int m = 0; m < 4; m++)
            #pragma unroll
            for (int rr = 0; rr < 4; rr++) {
                const int grow = row0 + wm + m * 16 + fg4 * 4 + rr;
                float v = acc[m][n][rr] + bias;
                if (which == 0) v *= 0.1803368801111204f; // HD^-0.5 * log2(e)
                const int t = grow >> 1, bb = grow & 1;
                dst[((size_t)(bb * H_ + hh) * T_ + t) * HD_ + hd] = f2bf(v);
            }
    }
}

// ---------- causal flash attention v7: T13 defer-max + max3 softmax ----------
__global__ __launch_bounds__(256) void k_attn(const unsigned short* __restrict__ Qb,
                                              const unsigned short* __restrict__ Kb,
                                              const unsigned short* __restrict__ Vt,
                                              unsigned short* __restrict__ aout) {
    __shared__ unsigned short Kl[3 * 4096];
    __shared__ unsigned short Vl[3 * 4096];
    const int id = blockIdx.x;
    const int qt = (id < 256) ? (15 - (id & 15)) : (id & 15);
    const int bh = (id >> 4) & 31;
    const int tid = threadIdx.x, w = tid >> 6, l = tid & 63;
    const int q5 = l & 31, hi = l >> 5, l7 = l & 7;
    const int row0 = w * 8 + (l >> 3);
    const int swz = ((l & 7) ^ (l >> 3)) * 8;
    const size_t base = (size_t)bh * T_ * HD_;
    const unsigned short* Qp = Qb + base;
    const unsigned short* kps = Kb + base + (size_t)row0 * HD_ + swz;
    const unsigned short* vps = Vt + base + (size_t)row0 * T_ + swz;
    const int qw0 = qt * 128 + w * 32;
    const int q = qw0 + q5;

    short8_t aq[4];
    #pragma unroll
    for (int khd = 0; khd < 4; ++khd)
        aq[khd] = *(const short8_t*)(Qp + (size_t)q * HD_ + khd * 16 + hi * 8);

    f32x16_t accO0, accO1;
    #pragma unroll
    for (int i = 0; i < 16; ++i) { accO0[i] = 0.f; accO1[i] = 0.f; }
    float mrun = -1e30f, lrun = 0.f;

    const int niter = (qt + 1) * 2;

#define STAGE_KV(t, b) { \
    const size_t ko = (size_t)(t) * 64 * HD_; const int vo = (t) * 64; \
    glds16(kps + ko,            Kl + (b) + w * 512); \
    glds16(kps + ko + 32 * HD_, Kl + (b) + 2048 + w * 512); \
    glds16(vps + vo,            Vl + (b) + w * 512); \
    glds16(vps + vo + 32 * T_,  Vl + (b) + 2048 + w * 512); }

    STAGE_KV(0, 0);
    STAGE_KV(1, 4096);
    unsigned c0 = 0, c1 = 4096, c2 = 8192;

    for (int it = 0; it < niter; ++it) {
        if (it < niter - 1) asm volatile("s_waitcnt vmcnt(4)" ::: "memory");
        else                asm volatile("s_waitcnt vmcnt(0)" ::: "memory");
        __builtin_amdgcn_s_barrier();
        __builtin_amdgcn_sched_barrier(0);
        if (it + 2 < niter) STAGE_KV(it + 2, c2);   // T14 issue-early
        const int s0 = it * 64;
        if (s0 <= qw0 + 31) {
            const unsigned short* KT = Kl + c0;
            const unsigned short* VT = Vl + c0;

            f32x16_t st0, st1;
            #pragma unroll
            for (int i = 0; i < 16; ++i) { st0[i] = 0.f; st1[i] = 0.f; }
            __builtin_amdgcn_s_setprio(1);
            #pragma unroll
            for (int khd = 0; khd < 4; ++khd) {
                const int cb = (khd * 16 + hi * 8) ^ (l7 * 8);
                const short8_t k0 = *(const short8_t*)(KT + q5 * 64 + cb);
                const short8_t k1 = *(const short8_t*)(KT + (32 + q5) * 64 + cb);
                st0 = __builtin_amdgcn_mfma_f32_32x32x16_bf16(k0, aq[khd], st0, 0, 0, 0);
                st1 = __builtin_amdgcn_mfma_f32_32x32x16_bf16(k1, aq[khd], st1, 0, 0, 0);
            }
            __builtin_amdgcn_s_setprio(0);

            // mask (uniform branch) + max via v_max3 chains
            const bool domask = (s0 + 63 > qw0);
            float pmax = -3e38f;
            if (domask) {
                #pragma unroll
                for (int r = 0; r < 16; ++r) {
                    const int kv0 = s0 + (r & 3) + 8 * (r >> 2) + 4 * hi;
                    float v0 = st0[r], v1 = st1[r];
                    if (kv0 > q)      v0 = -1e30f;
                    if (kv0 + 32 > q) v1 = -1e30f;
                    st0[r] = v0; st1[r] = v1;
                    pmax = fmaxf(fmaxf(pmax, v0), v1);   // v_max3
                }
            } else {
                #pragma unroll
                for (int r = 0; r < 16; ++r)
                    pmax = fmaxf(fmaxf(pmax, st0[r]), st1[r]);   // v_max3
            }
            pmax = fmaxf(pmax, __shfl_xor(pmax, 32));

            // T13 defer-max: rescale only when the running max grew by > 8 (exp2 domain)
            if (!__all(pmax - mrun <= 8.0f)) {
                const float mnew = fmaxf(mrun, pmax);
                const float scl = exp2f(mrun - mnew);
                lrun *= scl;
                #pragma unroll
                for (int i = 0; i < 16; ++i) { accO0[i] *= scl; accO1[i] *= scl; }
                mrun = mnew;
            }

            float pt0[16], pt1[16];
            float rs0 = 0.f, rs1 = 0.f;
            #pragma unroll
            for (int r = 0; r < 16; ++r) {
                pt0[r] = exp2f(st0[r] - mrun);
                pt1[r] = exp2f(st1[r] - mrun);
                rs0 += pt0[r]; rs1 += pt1[r];
            }
            float rs = rs0 + rs1;
            rs += __shfl_xor(rs, 32);
            lrun += rs;

            unsigned Wp[2][4][2];
            #pragma unroll
            for (int b = 0; b < 4; ++b) {
                Wp[0][b][0] = cvtpk(pt0[4 * b + 0], pt0[4 * b + 1]);
                Wp[0][b][1] = cvtpk(pt0[4 * b + 2], pt0[4 * b + 3]);
                Wp[1][b][0] = cvtpk(pt1[4 * b + 0], pt1[4 * b + 1]);
                Wp[1][b][1] = cvtpk(pt1[4 * b + 2], pt1[4 * b + 3]);
            }

            __builtin_amdgcn_s_setprio(1);
            #pragma unroll
            for (int ks = 0; ks < 4; ++ks) {
                const int t = ks >> 1, b0 = (ks & 1) * 2;
                const unsigned ownA0 = Wp[t][b0][0],     ownA1 = Wp[t][b0][1];
                const unsigned ownB0 = Wp[t][b0 + 1][0], ownB1 = Wp[t][b0 + 1][1];
                const unsigned send0 = hi ? ownA0 : ownB0;
                const unsigned send1 = hi ? ownA1 : ownB1;
                const unsigned recv0 = __shfl_xor(send0, 32);
                const unsigned recv1 = __shfl_xor(send1, 32);
                u32x4_t wds;
                wds[0] = hi ? recv0 : ownA0;
                wds[1] = hi ? recv1 : ownA1;
                wds[2] = hi ? ownB0 : recv0;
                wds[3] = hi ? ownB1 : recv1;
                const short8_t pfrag = __builtin_bit_cast(short8_t, wds);
                const int cb = (ks * 16 + hi * 8) ^ (l7 * 8);
                const short8_t v0 = *(const short8_t*)(VT + q5 * 64 + cb);
                const short8_t v1 = *(const short8_t*)(VT + (32 + q5) * 64 + cb);
                accO0 = __builtin_amdgcn_mfma_f32_32x32x16_bf16(v0, pfrag, accO0, 0, 0, 0);
                accO1 = __builtin_amdgcn_mfma_f32_32x32x16_bf16(v1, pfrag, accO1, 0, 0, 0);
            }
            __builtin_amdgcn_s_setprio(0);
        }
        const unsigned tb = c0; c0 = c1; c1 = c2; c2 = tb;
    }
#undef STAGE_KV

    const float linv = 1.f / lrun;
    const int bidx = bh >> 4, hidx = bh & 15;
    unsigned short* orow = aout + (size_t)(q * B_ + bidx) * D_ + hidx * 64;
    #pragma unroll
    for (int g = 0; g < 4; ++g) {
        const int hd0 = 8 * g + 4 * hi;
        unsigned long long pk0 =
              (unsigned long long)f2bf(accO0[4 * g + 0] * linv)
            | ((unsigned long long)f2bf(accO0[4 * g + 1] * linv) << 16)
            | ((unsigned long long)f2bf(accO0[4 * g + 2] * linv) << 32)
            | ((unsigned long long)f2bf(accO0[4 * g + 3] * linv) << 48);
        *(unsigned long long*)(orow + hd0) = pk0;
        unsigned long long pk1 =
              (unsigned long long)f2bf(accO1[4 * g + 0] * linv)
            | ((unsigned long long)f2bf(accO1[4 * g + 1] * linv) << 16)
            | ((unsigned long long)f2bf(accO1[4 * g + 2] * linv) << 32)
            | ((unsigned long long)f2bf(accO1[4 * g + 3] * linv) << 48);
        *(unsigned long long*)(orow + 32 + hd0) = pk1;
    }
}

// ---------- O-projection, split-K=2: x2 += aout @ Wo (atomic; x2 pre-init with x+bo) ----------
__global__ __launch_bounds__(256) void k_gemm_o(
    const unsigned short* __restrict__ A, const unsigned short* __restrict__ BT,
    float* __restrict__ x2) {
    __shared__ unsigned short Als[12288], Bls[12288];
    const int tid = threadIdx.x, w = tid >> 6, l = tid & 63;
    const int row0 = blockIdx.x * 128, col0 = blockIdx.y * 128;
    const int kc = blockIdx.z * 512;
    const int r0s = w * 16 + (l >> 2), r1s = 64 + w * 16 + (l >> 2);
    const int cs = ((l & 3) ^ ((l >> 3) & 3)) * 8;
    const unsigned short* ap0 = A + (size_t)(row0 + r0s) * D_ + kc + cs;
    const unsigned short* ap1 = A + (size_t)(row0 + r1s) * D_ + kc + cs;
    const unsigned short* bp0 = BT + (size_t)(col0 + r0s) * D_ + kc + cs;
    const unsigned short* bp1 = BT + (size_t)(col0 + r1s) * D_ + kc + cs;
    f32x4_t acc[4][4];
    gemm_core(ap0, ap1, bp0, bp1, 512, Als, Bls, acc);
    const int wm = (w >> 1) * 64, wn = (w & 1) * 64, fr = l & 15, fg4 = l >> 4;
    #pragma unroll
    for (int n = 0; n < 4; n++) {
        const int gcol = col0 + wn + n * 16 + fr;
        #pragma unroll
        for (int m = 0; m < 4; m++)
            #pragma unroll
            for (int rr = 0; rr < 4; rr++) {
                const int grow = row0 + wm + m * 16 + fg4 * 4 + rr;
                atomicAdd(&x2[(size_t)grow * D_ + gcol], acc[m][n][rr]);
            }
    }
}

// ---------- LN2 + gating + expert-LN; x2 <- x2 + u (in place) ----------
__global__ __launch_bounds__(256) void k_ln2_gate(
    float* __restrict__ x2, const float* __restrict__ g2, const float* __restrict__ b2,
    const float* __restrict__ cent, const float* __restrict__ eg, const float* __restrict__ eb,
    unsigned short* __restrict__ z, int* __restrict__ assign, int* __restrict__ counts) {
    __shared__ float sm[48];
    const int row = blockIdx.x, tid = threadIdx.x;
    const int w = tid >> 6, l = tid & 63;
    float* xr = x2 + (size_t)row * D_;
    const float4 v = *(const float4*)(xr + tid * 4);
    float s1 = v.x + v.y + v.z + v.w;
    float s2 = v.x * v.x + v.y * v.y + v.z * v.z + v.w * v.w;
    blockReduce2(s1, s2, sm);
    const float mean = s1 * (1.f / D_);
    const float inv  = rsqrtf(s2 * (1.f / D_) - mean * mean + 1e-5f);
    const float4 gg = *(const float4*)(g2 + tid * 4), bb = *(const float4*)(b2 + tid * 4);
    float4 u;
    u.x = (v.x - mean) * inv * gg.x + bb.x;
    u.y = (v.y - mean) * inv * gg.y + bb.y;
    u.z = (v.z - mean) * inv * gg.z + bb.z;
    u.w = (v.w - mean) * inv * gg.w + bb.w;
    float p[E_];
    #pragma unroll
    for (int e = 0; e < E_; e++) {
        const float4 c = *(const float4*)(cent + (size_t)e * D_ + tid * 4);
        p[e] = u.x * c.x + u.y * c.y + u.z * c.z + u.w * c.w;
    }
    #pragma unroll
    for (int m = 32; m; m >>= 1)
        #pragma unroll
        for (int e = 0; e < E_; e++) p[e] += __shfl_xor(p[e], m);
    __syncthreads();
    if (l == 0) {
        #pragma unroll
        for (int e = 0; e < E_; e++) sm[16 + e * 4 + w] = p[e];
    }
    __syncthreads();
    int best = 0; float bl = -1e30f;
    #pragma unroll
    for (int e = 0; e < E_; e++) {
        const float le = sm[16 + e * 4] + sm[16 + e * 4 + 1] + sm[16 + e * 4 + 2] + sm[16 + e * 4 + 3];
        if (le > bl) { bl = le; best = e; }
    }
    float t1 = u.x + u.y + u.z + u.w;
    float t2 = u.x * u.x + u.y * u.y + u.z * u.z + u.w * u.w;
    blockReduce2(t1, t2, sm);
    const float m2   = t1 * (1.f / D_);
    const float inv2 = rsqrtf(t2 * (1.f / D_) - m2 * m2 + 1e-5f);
    const float4 egv = *(const float4*)(eg + (size_t)best * D_ + tid * 4);
    const float4 ebv = *(const float4*)(eb + (size_t)best * D_ + tid * 4);
    unsigned long long pk =
          (unsigned long long)f2bf((u.x - m2) * inv2 * egv.x + ebv.x)
        | ((unsigned long long)f2bf((u.y - m2) * inv2 * egv.y + ebv.y) << 16)
        | ((unsigned long long)f2bf((u.z - m2) * inv2 * egv.z + ebv.z) << 32)
        | ((unsigned long long)f2bf((u.w - m2) * inv2 * egv.w + ebv.w) << 48);
    *(unsigned long long*)(z + (size_t)row * D_ + tid * 4) = pk;
    float4 xu; xu.x = v.x + u.x; xu.y = v.y + u.y; xu.z = v.z + u.z; xu.w = v.w + u.w;
    *(float4*)(xr + tid * 4) = xu;
    if (tid == 0) { assign[row] = best; atomicAdd(&counts[best], 1); }
}

// ---------- routing bookkeeping ----------
__global__ void k_offsets(const int* counts, int* pad_off) {
    if (threadIdx.x == 0) {
        int o = 0; pad_off[0] = 0;
        for (int e = 0; e < E_; e++) { o += ((counts[e] + 127) >> 7) << 7; pad_off[e + 1] = o; }
    }
}

__global__ void k_scatter(const int* assign, const int* pad_off, int* cursor, int* perm) {
    const int r = blockIdx.x * 256 + threadIdx.x;
    if (r >= N_) return;
    const int e = assign[r];
    const int pos = pad_off[e] + atomicAdd(&cursor[e], 1);
    perm[pos] = r;
}

// ---------- expert FFN GEMM 1: Y1 = relu(z[perm] @ W1_e + b1_e), bf16 ----------
__global__ __launch_bounds__(256) void k_gemm_e1(
    const unsigned short* __restrict__ z, const unsigned short* __restrict__ W1T,
    const float* __restrict__ eb1, const int* __restrict__ pad_off,
    const int* __restrict__ perm, unsigned short* __restrict__ Y1) {
    __shared__ unsigned short Als[12288], Bls[12288];
    const int tid = threadIdx.x, w = tid >> 6, l = tid & 63;
    const int col0 = blockIdx.x * 128, row0 = blockIdx.y * 128;
    if (row0 >= pad_off[E_]) return;
    int e = 0;
    while (row0 >= pad_off[e + 1]) e++;
    const int r0s = w * 16 + (l >> 2), r1s = 64 + w * 16 + (l >> 2);
    const int cs = ((l & 3) ^ ((l >> 3) & 3)) * 8;
    int pr0 = perm[row0 + r0s]; if (pr0 < 0) pr0 = 0;
    int pr1 = perm[row0 + r1s]; if (pr1 < 0) pr1 = 0;
    const unsigned short* ap0 = z + (size_t)pr0 * D_ + cs;
    const unsigned short* ap1 = z + (size_t)pr1 * D_ + cs;
    const unsigned short* BTe = W1T + (size_t)e * F_ * D_;
    const unsigned short* bp0 = BTe + (size_t)(col0 + r0s) * D_ + cs;
    const unsigned short* bp1 = BTe + (size_t)(col0 + r1s) * D_ + cs;
    f32x4_t acc[4][4];
    gemm_core(ap0, ap1, bp0, bp1, D_, Als, Bls, acc);
    const float* b1e = eb1 + (size_t)e * F_;
    const int wm = (w >> 1) * 64, wn = (w & 1) * 64, fr = l & 15, fg4 = l >> 4;
    #pragma unroll
    for (int n = 0; n < 4; n++) {
        const int gcol = col0 + wn + n * 16 + fr;
        const float bias = b1e[gcol];
        #pragma unroll
        for (int m = 0; m < 4; m++)
            #pragma unroll
            for (int rr = 0; rr < 4; rr++) {
                const int grow = row0 + wm + m * 16 + fg4 * 4 + rr;
                Y1[(size_t)grow * F_ + gcol] = f2bf(fmaxf(acc[m][n][rr] + bias, 0.f));
            }
    }
}

// ---------- expert FFN GEMM 2, split-K=2: out += Y1 @ W2_e (atomic; out pre-init) ----------
__global__ __launch_bounds__(256) void k_gemm_e2(
    const unsigned short* __restrict__ Y1, const unsigned short* __restrict__ W2T,
    const int* __restrict__ pad_off, const int* __restrict__ perm,
    float* __restrict__ out) {
    __shared__ unsigned short Als[12288], Bls[12288];
    const int tid = threadIdx.x, w = tid >> 6, l = tid & 63;
    const int row0 = blockIdx.x * 128, col0 = blockIdx.y * 128;
    const int kc = blockIdx.z * 2048;
    if (row0 >= pad_off[E_]) return;
    int e = 0;
    while (row0 >= pad_off[e + 1]) e++;
    const int r0s = w * 16 + (l >> 2), r1s = 64 + w * 16 + (l >> 2);
    const int cs = ((l & 3) ^ ((l >> 3) & 3)) * 8;
    const unsigned short* ap0 = Y1 + (size_t)(row0 + r0s) * F_ + kc + cs;
    const unsigned short* ap1 = Y1 + (size_t)(row0 + r1s) * F_ + kc + cs;
    const unsigned short* BTe = W2T + (size_t)e * D_ * F_;
    const unsigned short* bp0 = BTe + (size_t)(col0 + r0s) * F_ + kc + cs;
    const unsigned short* bp1 = BTe + (size_t)(col0 + r1s) * F_ + kc + cs;
    f32x4_t acc[4][4];
    gemm_core(ap0, ap1, bp0, bp1, 2048, Als, Bls, acc);
    const int wm = (w >> 1) * 64, wn = (w & 1) * 64, fr = l & 15, fg4 = l >> 4;
    #pragma unroll
    for (int n = 0; n < 4; n++) {
        const int gcol = col0 + wn + n * 16 + fr;
        #pragma unroll
        for (int m = 0; m < 4; m++)
            #pragma unroll
            for (int rr = 0; rr < 4; rr++) {
                const int grow = row0 + wm + m * 16 + fg4 * 4 + rr;
                const int rdst = perm[grow];
                if (rdst >= 0)
                    atomicAdd(&out[(size_t)rdst * D_ + gcol], acc[m][n][rr]);
            }
    }
}

extern "C" void kernel_launch(void* const* d_in, const int* in_sizes, int n_in,
                              void* d_out, int out_size, void* d_ws, size_t ws_size,
                              hipStream_t stream) {
    const float* x    = (const float*)d_in[0];
    const float* Wq   = (const float*)d_in[1];
    const float* bq   = (const float*)d_in[2];
    const float* Wk   = (const float*)d_in[3];
    const float* bk   = (const float*)d_in[4];
    const float* Wv   = (const float*)d_in[5];
    const float* bv   = (const float*)d_in[6];
    const float* Wo   = (const float*)d_in[7];
    const float* bo   = (const float*)d_in[8];
    const float* ln1g = (const float*)d_in[9];
    const float* ln1b = (const float*)d_in[10];
    const float* ln2g = (const float*)d_in[11];
    const float* ln2b = (const float*)d_in[12];
    const float* cent = (const float*)d_in[13];
    const float* egw  = (const float*)d_in[14];
    const float* ebw  = (const float*)d_in[15];
    const float* eW1  = (const float*)d_in[16];
    const float* eb1  = (const float*)d_in[17];
    const float* eW2  = (const float*)d_in[18];
    const float* eb2  = (const float*)d_in[19];
    float* out = (float*)d_out;

    char* W = (char*)d_ws;
    unsigned short* WqkvT = (unsigned short*)(W);                 //  6291456 B
    unsigned short* WoT   = (unsigned short*)(W + 6291456);       //  2097152 B
    unsigned short* Qb    = (unsigned short*)(W + 8388608);       //  8388608 B
    unsigned short* Kb    = (unsigned short*)(W + 16777216);      //  8388608 B
    unsigned short* Vb    = (unsigned short*)(W + 25165824);      //  8388608 B
    unsigned short* aout  = (unsigned short*)(W + 33554432);      //  8388608 B -> ends 41943040
    unsigned short* Y1    = (unsigned short*)(W);                 // 41943040 B (alias, all above dead)
    unsigned short* W1T   = (unsigned short*)(W + 41943040);      // 67108864 B
    unsigned short* W2T   = (unsigned short*)(W + 109051904);     // 67108864 B
    unsigned short* h1z   = (unsigned short*)(W + 176160768);     //  8388608 B (h1, later z)
    float*          x2    = (float*)(W + 184549376);              // 16777216 B -> ends 201326592
    unsigned short* Vt    = (unsigned short*)(W + 201326592);     //  8388608 B -> ends 209715200
    int*            assign= (int*)(W + 209715200);
    int*            perm  = (int*)(W + 209731584);
    int*            counts= (int*)(W + 209752064);
    int*            cursor= (int*)(W + 209752192);
    int*            pad_off=(int*)(W + 209752320);

    // weight transposes (fp32 -> bf16, B^T layout)
    k_transpose4<<<dim3(32, 32, 4), 256, 0, stream>>>(Wq, Wk, Wv, Wo, WqkvT, WoT);
    k_transpose<<<dim3(128, 32, 8), 256, 0, stream>>>(eW1, W1T, 1024, 4096);
    k_transpose<<<dim3(32, 128, 8), 256, 0, stream>>>(eW2, W2T, 4096, 1024);

    k_ln_x2<<<N_, 256, 0, stream>>>(x, ln1g, ln1b, bo, h1z, x2, counts, cursor, perm);
    k_gemm_qkv<<<dim3(24, 32), 256, 0, stream>>>(h1z, WqkvT, bq, bk, bv, Qb, Kb, Vb);
    k_transpose_v<<<dim3(32, 16), 256, 0, stream>>>(Vb, Vt);
    k_attn<<<dim3(512), 256, 0, stream>>>(Qb, Kb, Vt, aout);
    k_gemm_o<<<dim3(32, 8, 2), 256, 0, stream>>>(aout, WoT, x2);
    k_ln2_gate<<<N_, 256, 0, stream>>>(x2, ln2g, ln2b, cent, egw, ebw, h1z, assign, counts);
    k_offsets<<<1, 64, 0, stream>>>(counts, pad_off);
    k_scatter<<<16, 256, 0, stream>>>(assign, pad_off, cursor, perm);
    k_init_out<<<N_, 256, 0, stream>>>(x2, eb2, assign, out);
    k_gemm_e1<<<dim3(32, 40), 256, 0, stream>>>(h1z, W1T, eb1, pad_off, perm, Y1);
    k_gemm_e2<<<dim3(40, 8, 2), 256, 0, stream>>>(Y1, W2T, pad_off, perm, out);
}